// Round 15
// baseline (503.628 us; speedup 1.0000x reference)
//
#include <hip/hip_runtime.h>
#include <hip/hip_bf16.h>

#define NN 50000
#define NE 800000
#define ET (NE + NN)          // 850000 edges incl. self-loops
#define NG 64
#define IND 128
#define HD 64
#define NH 4
#define D1 256                // NH*HD
#define BN_EPS 1e-5f
#define SLOPE 0.2f
#define PW_NODES 25           // nodes per wave in k_bn2pool (2000 waves)
#define LOG2E 1.4426950408889634f

typedef unsigned short u16;
typedef __attribute__((ext_vector_type(8))) short bf16x8;
typedef __attribute__((ext_vector_type(4))) float f32x4;

__device__ __forceinline__ float b2f(u16 u){
  union { unsigned int i; float f; } c; c.i = ((unsigned int)u) << 16; return c.f;
}
__device__ __forceinline__ u16 f2b(float f){
  unsigned int u = __float_as_uint(f);
  u = (u + 0x7FFF + ((u >> 16) & 1)) >> 16;   // round-to-nearest-even
  return (u16)u;
}

// ---------------- mega-prep: casts + weight transposes + zeroing ----------------
#define PX   (NN*IND/4)            // 1,600,000  x -> bf16 (float4 chunks)
#define PW1  (2*D1*(IND/4))        // 16,384     Wt1
#define PW2  (2*HD*(D1/4))         // 8,192      Wt2
#define PZC  NN                    // 50,000     zero cur
#define PZS  (2*D1 + 2*HD + NG*HD + NG)  // 4,800 zero floats
#define PTOT (PX + PW1 + PW2 + PZC + PZS)

__global__ void k_prep(const float* __restrict__ x, u16* __restrict__ xb,
      const float* __restrict__ W1a, const float* __restrict__ W1b, u16* __restrict__ Wt1,
      const float* __restrict__ W2a, const float* __restrict__ W2b, u16* __restrict__ Wt2,
      int* __restrict__ cur, float* __restrict__ stats1, float* __restrict__ stats2,
      float* __restrict__ pool, float* __restrict__ pcnt){
  int id = blockIdx.x*256 + threadIdx.x;
  if (id < PX){
    float4 v = reinterpret_cast<const float4*>(x)[id];
    ushort4 o; o.x = f2b(v.x); o.y = f2b(v.y); o.z = f2b(v.z); o.w = f2b(v.w);
    reinterpret_cast<ushort4*>(xb)[id] = o;
    return;
  }
  id -= PX;
  if (id < PW1){
    int c  = id % (2*D1);
    int k4 = (id / (2*D1))*4;
    const float* W = (c < D1) ? W1a : W1b;
    int cl = (c < D1) ? c : c - D1;
    ushort4 o;
    o.x = f2b(W[(size_t)(k4+0)*D1 + cl]);
    o.y = f2b(W[(size_t)(k4+1)*D1 + cl]);
    o.z = f2b(W[(size_t)(k4+2)*D1 + cl]);
    o.w = f2b(W[(size_t)(k4+3)*D1 + cl]);
    *reinterpret_cast<ushort4*>(&Wt1[(size_t)c*IND + k4]) = o;
    return;
  }
  id -= PW1;
  if (id < PW2){
    int c  = id % (2*HD);
    int k4 = (id / (2*HD))*4;
    const float* W = (c < HD) ? W2a : W2b;
    int cl = (c < HD) ? c : c - HD;
    ushort4 o;
    o.x = f2b(W[(size_t)(k4+0)*HD + cl]);
    o.y = f2b(W[(size_t)(k4+1)*HD + cl]);
    o.z = f2b(W[(size_t)(k4+2)*HD + cl]);
    o.w = f2b(W[(size_t)(k4+3)*HD + cl]);
    *reinterpret_cast<ushort4*>(&Wt2[(size_t)c*D1 + k4]) = o;
    return;
  }
  id -= PW2;
  if (id < PZC){ cur[id] = 0; return; }
  id -= PZC;
  if (id < 2*D1){ stats1[id] = 0.f; return; }
  id -= 2*D1;
  if (id < 2*HD){ stats2[id] = 0.f; return; }
  id -= 2*HD;
  if (id < NG*HD){ pool[id] = 0.f; return; }
  id -= NG*HD;
  if (id < NG) pcnt[id] = 0.f;
}

// ---------------- CSR build (by dst) ----------------
__global__ void k_count(const int* __restrict__ ei, int* __restrict__ cnt){
  int e = blockIdx.x*256 + threadIdx.x;
  if (e >= ET) return;
  int d = (e < NE) ? ei[NE + e] : (e - NE);
  atomicAdd(&cnt[d], 1);
}

// single-block exclusive scan of cur -> ro; re-zeroes cur for scatter
__global__ __launch_bounds__(1024) void k_scan(int* __restrict__ cur, int* __restrict__ ro){
  __shared__ int s[1024];
  const int CH = (NN + 1023)/1024;   // 49
  int t = threadIdx.x;
  int base = t*CH;
  int sum = 0;
  for (int i = 0; i < CH; i++){
    int idx = base + i;
    if (idx < NN) sum += cur[idx];
  }
  s[t] = sum;
  __syncthreads();
  for (int off = 1; off < 1024; off <<= 1){
    int v = (t >= off) ? s[t - off] : 0;
    __syncthreads();
    s[t] += v;
    __syncthreads();
  }
  int pre = s[t] - sum;              // exclusive prefix
  for (int i = 0; i < CH; i++){
    int idx = base + i;
    if (idx < NN){
      int c = cur[idx];
      ro[idx] = pre;
      pre += c;
      cur[idx] = 0;
    }
  }
  if (t == 1023) ro[NN] = ET;
}

__global__ void k_scatter(const int* __restrict__ ei, const int* __restrict__ ro,
                          int* __restrict__ cur, int* __restrict__ ssrc){
  int e = blockIdx.x*256 + threadIdx.x;
  if (e >= ET) return;
  int s, d;
  if (e < NE){ s = ei[e]; d = ei[NE + e]; } else { s = e - NE; d = s; }
  int pos = ro[d] + atomicAdd(&cur[d], 1);
  ssrc[pos] = s;
}

// ---------------- MFMA dual GEMM (bf16 in, bf16 out); optional fused BN+ELU on A ----------------
template<int KT, int NOUT, bool BN>
__global__ __launch_bounds__(256) void k_gemm(const u16* __restrict__ Ab,
      const u16* __restrict__ Wt, const float* __restrict__ ba, const float* __restrict__ bb,
      const float* __restrict__ stats, const float* __restrict__ gamma, const float* __restrict__ beta,
      u16* __restrict__ Ca, u16* __restrict__ Cb){
  __shared__ u16 As[64][32];
  __shared__ u16 Bs[128][32];
  __shared__ float scl[KT];
  __shared__ float shl[KT];
  int t = threadIdx.x;
  int lane = t & 63;
  int w = t >> 6;
  int wm = w >> 1, wn = w & 1;
  int n0 = blockIdx.x*64;
  int cb0 = blockIdx.y*128;

  if constexpr (BN){
    for (int c = t; c < KT; c += 256){
      float mu = stats[c]*(1.f/NN);
      float var = stats[KT + c]*(1.f/NN) - mu*mu;
      float g = gamma[c]*rsqrtf(var + BN_EPS);
      scl[c] = g;
      shl[c] = beta[c] - mu*g;
    }
    __syncthreads();
  }

  f32x4 acc[2][4];
  #pragma unroll
  for (int i = 0; i < 2; i++)
    #pragma unroll
    for (int j = 0; j < 4; j++) acc[i][j] = (f32x4){0.f,0.f,0.f,0.f};

  int sr = t >> 3;          // staging row/col 0..31
  int k4 = (t & 7)*4;       // staging k chunk
  int fm = lane & 15;       // fragment row/col
  int fk = (lane >> 4)*8;   // fragment k base

  for (int kb = 0; kb < KT/32; kb++){
    int kbase = kb*32;
    #pragma unroll
    for (int p = 0; p < 2; p++){
      int r = sr + p*32;
      int gn = n0 + r;
      ushort4 v = make_ushort4(0,0,0,0);
      if (gn < NN) v = *reinterpret_cast<const ushort4*>(&Ab[(size_t)gn*KT + kbase + k4]);
      if constexpr (BN){
        int c0 = kbase + k4;
        float f0 = b2f(v.x)*scl[c0+0] + shl[c0+0]; f0 = (f0 > 0.f) ? f0 : (__expf(f0) - 1.f);
        float f1 = b2f(v.y)*scl[c0+1] + shl[c0+1]; f1 = (f1 > 0.f) ? f1 : (__expf(f1) - 1.f);
        float f2 = b2f(v.z)*scl[c0+2] + shl[c0+2]; f2 = (f2 > 0.f) ? f2 : (__expf(f2) - 1.f);
        float f3 = b2f(v.w)*scl[c0+3] + shl[c0+3]; f3 = (f3 > 0.f) ? f3 : (__expf(f3) - 1.f);
        v.x = f2b(f0); v.y = f2b(f1); v.z = f2b(f2); v.w = f2b(f3);
      }
      *reinterpret_cast<ushort4*>(&As[r][k4]) = v;
    }
    #pragma unroll
    for (int q = 0; q < 4; q++){
      int cn = sr + q*32;
      ushort4 v = *reinterpret_cast<const ushort4*>(&Wt[(size_t)(cb0+cn)*KT + kbase + k4]);
      *reinterpret_cast<ushort4*>(&Bs[cn][k4]) = v;
    }
    __syncthreads();
    bf16x8 af0 = *reinterpret_cast<const bf16x8*>(&As[wm*32 + fm][fk]);
    bf16x8 af1 = *reinterpret_cast<const bf16x8*>(&As[wm*32 + 16 + fm][fk]);
    #pragma unroll
    for (int nt = 0; nt < 4; nt++){
      bf16x8 bfr = *reinterpret_cast<const bf16x8*>(&Bs[wn*64 + nt*16 + fm][fk]);
      acc[0][nt] = __builtin_amdgcn_mfma_f32_16x16x32_bf16(af0, bfr, acc[0][nt], 0, 0, 0);
      acc[1][nt] = __builtin_amdgcn_mfma_f32_16x16x32_bf16(af1, bfr, acc[1][nt], 0, 0, 0);
    }
    __syncthreads();
  }

  // epilogue: C/D layout col=lane&15, row=(lane>>4)*4+reg  [m89-verified]
  int frow = (lane >> 4)*4;
  #pragma unroll
  for (int nt = 0; nt < 4; nt++){
    int cn = cb0 + wn*64 + nt*16 + fm;
    bool first = (cn < NOUT);
    int cl = first ? cn : cn - NOUT;
    float bv = first ? ba[cl] : bb[cl];
    u16* Cp = first ? Ca : Cb;
    #pragma unroll
    for (int mt = 0; mt < 2; mt++){
      #pragma unroll
      for (int r = 0; r < 4; r++){
        int grow = n0 + wm*32 + mt*16 + frow + r;
        if (grow < NN) Cp[(size_t)grow*NOUT + cl] = f2b(acc[mt][nt][r] + bv);
      }
    }
  }
}

// ---- Fused GATv2 layer 1: 4x edge unroll; bf16 output (R13 scalar version) ----
__global__ __launch_bounds__(256) void k_gat1(const int* __restrict__ ro, const int* __restrict__ ssrc,
      const u16* __restrict__ xl, const u16* __restrict__ xr,
      const float* __restrict__ att, const float* __restrict__ bias,
      u16* __restrict__ out){
  int widx = threadIdx.x >> 6, lane = threadIdx.x & 63;
  int n = blockIdx.x*4 + widx;
  if (n >= NN) return;
  int base = (lane >> 4)*HD + (lane & 15)*4;
  ushort4 ur = *reinterpret_cast<const ushort4*>(&xr[(size_t)n*D1 + base]);
  float xr0 = b2f(ur.x), xr1 = b2f(ur.y), xr2 = b2f(ur.z), xr3 = b2f(ur.w);
  float4 at4 = *reinterpret_cast<const float4*>(&att[base]);
  float a1x = 0.6f*LOG2E*at4.x, a2x = 0.4f*LOG2E*at4.x;
  float a1y = 0.6f*LOG2E*at4.y, a2y = 0.4f*LOG2E*at4.y;
  float a1z = 0.6f*LOG2E*at4.z, a2z = 0.4f*LOG2E*at4.z;
  float a1w = 0.6f*LOG2E*at4.w, a2w = 0.4f*LOG2E*at4.w;
  float m = -1e30f, den = 0.f;
  float ax=0.f, ay=0.f, az=0.f, aw=0.f;
  int b = ro[n], e = ro[n+1];
  int i = b;
  for (; i + 3 < e; i += 4){
    int s0 = ssrc[i], s1 = ssrc[i+1], s2 = ssrc[i+2], s3 = ssrc[i+3];
    ushort4 u0 = *reinterpret_cast<const ushort4*>(&xl[(size_t)s0*D1 + base]);
    ushort4 u1 = *reinterpret_cast<const ushort4*>(&xl[(size_t)s1*D1 + base]);
    ushort4 u2 = *reinterpret_cast<const ushort4*>(&xl[(size_t)s2*D1 + base]);
    ushort4 u3 = *reinterpret_cast<const ushort4*>(&xl[(size_t)s3*D1 + base]);
    float v0x=b2f(u0.x), v0y=b2f(u0.y), v0z=b2f(u0.z), v0w=b2f(u0.w);
    float v1x=b2f(u1.x), v1y=b2f(u1.y), v1z=b2f(u1.z), v1w=b2f(u1.w);
    float v2x=b2f(u2.x), v2y=b2f(u2.y), v2z=b2f(u2.z), v2w=b2f(u2.w);
    float v3x=b2f(u3.x), v3y=b2f(u3.y), v3z=b2f(u3.z), v3w=b2f(u3.w);
    float t0, t1, t2, t3;
    float L0, L1, L2, L3;
    t0 = v0x+xr0; t1 = v0y+xr1; t2 = v0z+xr2; t3 = v0w+xr3;
    L0 = fmaf(a1x,t0, a2x*fabsf(t0));
    L0 = fmaf(a1y,t1, fmaf(a2y,fabsf(t1), L0));
    L0 = fmaf(a1z,t2, fmaf(a2z,fabsf(t2), L0));
    L0 = fmaf(a1w,t3, fmaf(a2w,fabsf(t3), L0));
    t0 = v1x+xr0; t1 = v1y+xr1; t2 = v1z+xr2; t3 = v1w+xr3;
    L1 = fmaf(a1x,t0, a2x*fabsf(t0));
    L1 = fmaf(a1y,t1, fmaf(a2y,fabsf(t1), L1));
    L1 = fmaf(a1z,t2, fmaf(a2z,fabsf(t2), L1));
    L1 = fmaf(a1w,t3, fmaf(a2w,fabsf(t3), L1));
    t0 = v2x+xr0; t1 = v2y+xr1; t2 = v2z+xr2; t3 = v2w+xr3;
    L2 = fmaf(a1x,t0, a2x*fabsf(t0));
    L2 = fmaf(a1y,t1, fmaf(a2y,fabsf(t1), L2));
    L2 = fmaf(a1z,t2, fmaf(a2z,fabsf(t2), L2));
    L2 = fmaf(a1w,t3, fmaf(a2w,fabsf(t3), L2));
    t0 = v3x+xr0; t1 = v3y+xr1; t2 = v3z+xr2; t3 = v3w+xr3;
    L3 = fmaf(a1x,t0, a2x*fabsf(t0));
    L3 = fmaf(a1y,t1, fmaf(a2y,fabsf(t1), L3));
    L3 = fmaf(a1z,t2, fmaf(a2z,fabsf(t2), L3));
    L3 = fmaf(a1w,t3, fmaf(a2w,fabsf(t3), L3));
    #pragma unroll
    for (int off = 1; off <= 8; off <<= 1){
      L0 += __shfl_xor(L0, off); L1 += __shfl_xor(L1, off);
      L2 += __shfl_xor(L2, off); L3 += __shfl_xor(L3, off);
    }
    float Lm = fmaxf(fmaxf(L0, L1), fmaxf(L2, L3));
    if (__any(Lm > m + 8.f)){
      float mn = fmaxf(m, Lm);
      float corr = exp2f(m - mn);
      den *= corr; ax *= corr; ay *= corr; az *= corr; aw *= corr;
      m = mn;
    }
    float p0 = exp2f(L0 - m), p1 = exp2f(L1 - m);
    float p2 = exp2f(L2 - m), p3 = exp2f(L3 - m);
    den += (p0 + p1) + (p2 + p3);
    ax = fmaf(p0,v0x, fmaf(p1,v1x, fmaf(p2,v2x, fmaf(p3,v3x, ax))));
    ay = fmaf(p0,v0y, fmaf(p1,v1y, fmaf(p2,v2y, fmaf(p3,v3y, ay))));
    az = fmaf(p0,v0z, fmaf(p1,v1z, fmaf(p2,v2z, fmaf(p3,v3z, az))));
    aw = fmaf(p0,v0w, fmaf(p1,v1w, fmaf(p2,v2w, fmaf(p3,v3w, aw))));
  }
  for (; i < e; i++){
    int s = ssrc[i];
    ushort4 u = *reinterpret_cast<const ushort4*>(&xl[(size_t)s*D1 + base]);
    float vx = b2f(u.x), vy = b2f(u.y), vz = b2f(u.z), vw = b2f(u.w);
    float t0 = vx + xr0, t1 = vy + xr1, t2 = vz + xr2, t3 = vw + xr3;
    float L;
    L = fmaf(a1x, t0, a2x*fabsf(t0));
    L = fmaf(a1y, t1, fmaf(a2y, fabsf(t1), L));
    L = fmaf(a1z, t2, fmaf(a2z, fabsf(t2), L));
    L = fmaf(a1w, t3, fmaf(a2w, fabsf(t3), L));
    L += __shfl_xor(L, 1); L += __shfl_xor(L, 2);
    L += __shfl_xor(L, 4); L += __shfl_xor(L, 8);
    if (__any(L > m + 8.f)){
      float mn = fmaxf(m, L);
      float corr = exp2f(m - mn);
      den *= corr; ax *= corr; ay *= corr; az *= corr; aw *= corr;
      m = mn;
    }
    float p = exp2f(L - m);
    den += p;
    ax = fmaf(p, vx, ax);
    ay = fmaf(p, vy, ay);
    az = fmaf(p, vz, az);
    aw = fmaf(p, vw, aw);
  }
  float inv = 1.f/den;
  float4 b4 = *reinterpret_cast<const float4*>(&bias[base]);
  ushort4 o;
  o.x = f2b(ax*inv + b4.x); o.y = f2b(ay*inv + b4.y);
  o.z = f2b(az*inv + b4.z); o.w = f2b(aw*inv + b4.w);
  *reinterpret_cast<ushort4*>(&out[(size_t)n*D1 + base]) = o;
}

// ---------------- BatchNorm stats ----------------
__global__ __launch_bounds__(256) void k_bnstats16(const u16* __restrict__ h, float* __restrict__ stats,
                                                   int ncols, int rpb){
  int nrl = 256/ncols;
  int c = threadIdx.x % ncols;
  int rl = threadIdx.x / ncols;
  int r0 = blockIdx.x*rpb + rl;
  int r1 = min(NN, (blockIdx.x+1)*rpb);
  float s = 0.f, s2 = 0.f;
  for (int r = r0; r < r1; r += nrl){
    float v = b2f(h[(size_t)r*ncols + c]);
    s += v; s2 += v*v;
  }
  atomicAdd(&stats[c], s);
  atomicAdd(&stats[ncols + c], s2);
}

__global__ __launch_bounds__(256) void k_bnstats(const float* __restrict__ h, float* __restrict__ stats,
                                                 int ncols, int rpb){
  int nrl = 256/ncols;
  int c = threadIdx.x % ncols;
  int rl = threadIdx.x / ncols;
  int r0 = blockIdx.x*rpb + rl;
  int r1 = min(NN, (blockIdx.x+1)*rpb);
  float s = 0.f, s2 = 0.f;
  for (int r = r0; r < r1; r += nrl){
    float v = h[(size_t)r*ncols + c];
    s += v; s2 += v*v;
  }
  atomicAdd(&stats[c], s);
  atomicAdd(&stats[ncols + c], s2);
}

// ---- Fused GATv2 layer 2 (1 head): 4 lane-groups, 2x unroll (R13 scalar version) ----
__global__ __launch_bounds__(256) void k_gat2(const int* __restrict__ ro, const int* __restrict__ ssrc,
      const u16* __restrict__ xl, const u16* __restrict__ xr,
      const float* __restrict__ att, const float* __restrict__ bias,
      float* __restrict__ out){
  int widx = threadIdx.x >> 6, lane = threadIdx.x & 63;
  int n = blockIdx.x*4 + widx;
  if (n >= NN) return;
  int g = lane >> 4, c4 = (lane & 15)*4;
  ushort4 ur = *reinterpret_cast<const ushort4*>(&xr[(size_t)n*HD + c4]);
  float xr0 = b2f(ur.x), xr1 = b2f(ur.y), xr2 = b2f(ur.z), xr3 = b2f(ur.w);
  float4 at4 = *reinterpret_cast<const float4*>(&att[c4]);
  float a1x = 0.6f*LOG2E*at4.x, a2x = 0.4f*LOG2E*at4.x;
  float a1y = 0.6f*LOG2E*at4.y, a2y = 0.4f*LOG2E*at4.y;
  float a1z = 0.6f*LOG2E*at4.z, a2z = 0.4f*LOG2E*at4.z;
  float a1w = 0.6f*LOG2E*at4.w, a2w = 0.4f*LOG2E*at4.w;
  float m = -1e30f, den = 0.f;
  float ax=0.f, ay=0.f, az=0.f, aw=0.f;
  int b = ro[n], e = ro[n+1];
  int i = b + g;
  for (; i + 4 < e; i += 8){
    int s0 = ssrc[i], s1 = ssrc[i+4];
    ushort4 u0 = *reinterpret_cast<const ushort4*>(&xl[(size_t)s0*HD + c4]);
    ushort4 u1 = *reinterpret_cast<const ushort4*>(&xl[(size_t)s1*HD + c4]);
    float v0x=b2f(u0.x), v0y=b2f(u0.y), v0z=b2f(u0.z), v0w=b2f(u0.w);
    float v1x=b2f(u1.x), v1y=b2f(u1.y), v1z=b2f(u1.z), v1w=b2f(u1.w);
    float t0, t1, t2, t3, L0, L1;
    t0 = v0x+xr0; t1 = v0y+xr1; t2 = v0z+xr2; t3 = v0w+xr3;
    L0 = fmaf(a1x,t0, a2x*fabsf(t0));
    L0 = fmaf(a1y,t1, fmaf(a2y,fabsf(t1), L0));
    L0 = fmaf(a1z,t2, fmaf(a2z,fabsf(t2), L0));
    L0 = fmaf(a1w,t3, fmaf(a2w,fabsf(t3), L0));
    t0 = v1x+xr0; t1 = v1y+xr1; t2 = v1z+xr2; t3 = v1w+xr3;
    L1 = fmaf(a1x,t0, a2x*fabsf(t0));
    L1 = fmaf(a1y,t1, fmaf(a2y,fabsf(t1), L1));
    L1 = fmaf(a1z,t2, fmaf(a2z,fabsf(t2), L1));
    L1 = fmaf(a1w,t3, fmaf(a2w,fabsf(t3), L1));
    #pragma unroll
    for (int off = 1; off <= 8; off <<= 1){
      L0 += __shfl_xor(L0, off); L1 += __shfl_xor(L1, off);
    }
    float Lm = fmaxf(L0, L1);
    if (__any(Lm > m + 8.f)){
      float mn = fmaxf(m, Lm);
      float corr = exp2f(m - mn);
      den *= corr; ax *= corr; ay *= corr; az *= corr; aw *= corr;
      m = mn;
    }
    float p0 = exp2f(L0 - m), p1 = exp2f(L1 - m);
    den += p0 + p1;
    ax = fmaf(p0, v0x, fmaf(p1, v1x, ax));
    ay = fmaf(p0, v0y, fmaf(p1, v1y, ay));
    az = fmaf(p0, v0z, fmaf(p1, v1z, az));
    aw = fmaf(p0, v0w, fmaf(p1, v1w, aw));
  }
  for (; i < e; i += 4){
    int s = ssrc[i];
    ushort4 u = *reinterpret_cast<const ushort4*>(&xl[(size_t)s*HD + c4]);
    float vx = b2f(u.x), vy = b2f(u.y), vz = b2f(u.z), vw = b2f(u.w);
    float t0 = vx + xr0, t1 = vy + xr1, t2 = vz + xr2, t3 = vw + xr3;
    float L;
    L = fmaf(a1x, t0, a2x*fabsf(t0));
    L = fmaf(a1y, t1, fmaf(a2y, fabsf(t1), L));
    L = fmaf(a1z, t2, fmaf(a2z, fabsf(t2), L));
    L = fmaf(a1w, t3, fmaf(a2w, fabsf(t3), L));
    L += __shfl_xor(L, 1); L += __shfl_xor(L, 2);
    L += __shfl_xor(L, 4); L += __shfl_xor(L, 8);
    if (__any(L > m + 8.f)){
      float mn = fmaxf(m, L);
      float corr = exp2f(m - mn);
      den *= corr; ax *= corr; ay *= corr; az *= corr; aw *= corr;
      m = mn;
    }
    float p = exp2f(L - m);
    den += p;
    ax = fmaf(p, vx, ax);
    ay = fmaf(p, vy, ay);
    az = fmaf(p, vz, az);
    aw = fmaf(p, vw, aw);
  }
  // exact merge of the 4 per-group partials (lanes l^16 / l^32 share c4)
  #pragma unroll
  for (int off = 16; off <= 32; off <<= 1){
    float mo  = __shfl_xor(m, off);
    float dno = __shfl_xor(den, off);
    float bx  = __shfl_xor(ax, off);
    float by  = __shfl_xor(ay, off);
    float bz  = __shfl_xor(az, off);
    float bw  = __shfl_xor(aw, off);
    float mn = fmaxf(m, mo);
    float c1 = exp2f(m - mn), c2 = exp2f(mo - mn);
    den = den*c1 + dno*c2;
    ax = ax*c1 + bx*c2;
    ay = ay*c1 + by*c2;
    az = az*c1 + bz*c2;
    aw = aw*c1 + bw*c2;
    m = mn;
  }
  float inv = 1.f/den;
  float4 b4 = *reinterpret_cast<const float4*>(&bias[c4]);
  float4 o = make_float4(ax*inv + b4.x, ay*inv + b4.y, az*inv + b4.z, aw*inv + b4.w);
  *reinterpret_cast<float4*>(&out[(size_t)n*HD + c4]) = o;
}

// BN2 + ELU + pooled sums, sorted-batch strip reduction (25 nodes/wave)
__global__ __launch_bounds__(256) void k_bn2pool(const float* __restrict__ h2, const float* __restrict__ stats,
      const float* __restrict__ gamma, const float* __restrict__ beta,
      const int* __restrict__ batch, float* __restrict__ pool, float* __restrict__ pcnt){
  int wave = blockIdx.x*4 + (threadIdx.x >> 6);
  int lane = threadIdx.x & 63;
  int n0 = wave*PW_NODES;
  if (n0 >= NN) return;
  int n1 = min(NN, n0 + PW_NODES);
  const float invn = 1.f/NN;
  float mu = stats[lane]*invn;
  float var = stats[HD + lane]*invn - mu*mu;
  float sc = gamma[lane]*rsqrtf(var + BN_EPS);
  float sh = beta[lane] - mu*sc;
  int curg = batch[n0];
  float acc = 0.f, cnt = 0.f;
  for (int n = n0; n < n1; n++){
    int g = batch[n];
    if (g != curg){
      atomicAdd(&pool[curg*HD + lane], acc);
      if (lane == 0) atomicAdd(&pcnt[curg], cnt);
      acc = 0.f; cnt = 0.f; curg = g;
    }
    float v = h2[(size_t)n*HD + lane]*sc + sh;
    v = (v > 0.f) ? v : (__expf(v) - 1.f);
    acc += v; cnt += 1.f;
  }
  atomicAdd(&pool[curg*HD + lane], acc);
  if (lane == 0) atomicAdd(&pcnt[curg], cnt);
}

// final MLP: out[g] = elu(pooled@lw1+lb1) @ lw2 + lb2   (f32 output)
__global__ __launch_bounds__(64) void k_mlp(const float* __restrict__ pool, const float* __restrict__ pcnt,
      const float* __restrict__ lw1, const float* __restrict__ lb1,
      const float* __restrict__ lw2, const float* __restrict__ lb2, float* __restrict__ out){
  __shared__ float p[HD];
  int g = blockIdx.x, c = threadIdx.x;
  float cnt = fmaxf(pcnt[g], 1.f);
  p[c] = pool[g*HD + c]/cnt;
  __syncthreads();
  float acc = lb1[c];
  for (int k = 0; k < HD; k++) acc += p[k]*lw1[k*HD + c];
  acc = (acc > 0.f) ? acc : (__expf(acc) - 1.f);
  float t = acc * lw2[c];
  #pragma unroll
  for (int off = 32; off > 0; off >>= 1) t += __shfl_xor(t, off, 64);
  if (c == 0) out[g] = t + lb2[0];
}

extern "C" void kernel_launch(void* const* d_in, const int* in_sizes, int n_in,
                              void* d_out, int out_size, void* d_ws, size_t ws_size,
                              hipStream_t stream){
  const float* x    = (const float*)d_in[0];
  const int*  ei    = (const int*) d_in[1];
  const int*  batch = (const int*) d_in[2];
  const float* W1l = (const float*)d_in[3];
  const float* b1l = (const float*)d_in[4];
  const float* W1r = (const float*)d_in[5];
  const float* b1r = (const float*)d_in[6];
  const float* att1= (const float*)d_in[7];
  const float* bias1=(const float*)d_in[8];
  const float* gamma1=(const float*)d_in[9];
  const float* beta1 =(const float*)d_in[10];
  const float* W2l = (const float*)d_in[11];
  const float* b2l = (const float*)d_in[12];
  const float* W2r = (const float*)d_in[13];
  const float* b2r = (const float*)d_in[14];
  const float* att2= (const float*)d_in[15];
  const float* bias2=(const float*)d_in[16];
  const float* gamma2=(const float*)d_in[17];
  const float* beta2 =(const float*)d_in[18];
  const float* lw1 = (const float*)d_in[19];
  const float* lb1 = (const float*)d_in[20];
  const float* lw2 = (const float*)d_in[21];
  const float* lb2 = (const float*)d_in[22];
  float* out = (float*)d_out;

  char* w = (char*)d_ws;
  size_t off = 0;
  auto take = [&](size_t bytes)->char*{
    char* p = w + off;
    off = (off + bytes + 255) & ~(size_t)255;
    return p;
  };
  int*   ro    = (int*)  take((NN+1)*sizeof(int));
  int*   cur   = (int*)  take((size_t)NN*sizeof(int));
  int*   ssrc  = (int*)  take((size_t)ET*sizeof(int));
  float* stats1= (float*)take(2*D1*sizeof(float));
  float* stats2= (float*)take(2*HD*sizeof(float));
  float* pool  = (float*)take(NG*HD*sizeof(float));
  float* pcnt  = (float*)take(NG*sizeof(float));
  u16*   xb    = (u16*)  take((size_t)NN*IND*sizeof(u16));
  u16*   Wt1   = (u16*)  take((size_t)2*D1*IND*sizeof(u16));   // [512][128]
  u16*   Wt2   = (u16*)  take((size_t)2*HD*D1*sizeof(u16));    // [128][256]
  char*  bufA  = take((size_t)NN*D1*2*sizeof(u16));            // xlb1+xrb1; later xlb2+xrb2+h2
  u16*   h1    = (u16*)  take((size_t)NN*D1*sizeof(u16));      // bf16 h1 (raw, pre-BN)

  u16* xlb1 = (u16*)bufA;
  u16* xrb1 = xlb1 + (size_t)NN*D1;
  u16* xlb2 = (u16*)bufA;                                      // overlays dead xlb1
  u16* xrb2 = xlb2 + (size_t)NN*HD;
  float* h2 = (float*)(bufA + (size_t)2*NN*HD*sizeof(u16));

  // mega-prep: casts + weight transposes + zero cur/stats/pool/pcnt
  k_prep<<<(PTOT + 255)/256, 256, 0, stream>>>(x, xb, W1l, W1r, Wt1, W2l, W2r, Wt2,
                                               cur, stats1, stats2, pool, pcnt);

  // CSR build: count -> single-block scan (re-zeroes cur) -> scatter
  k_count<<<(ET+255)/256, 256, 0, stream>>>(ei, cur);
  k_scan<<<1, 1024, 0, stream>>>(cur, ro);
  k_scatter<<<(ET+255)/256, 256, 0, stream>>>(ei, ro, cur, ssrc);

  const int MB = (NN + 63)/64;                      // 782 row tiles

  // Layer 1: MFMA dual GEMM (bf16) then fused gather+softmax+aggregate
  k_gemm<IND, D1, false><<<dim3(MB, 4), 256, 0, stream>>>(xb, Wt1, b1l, b1r,
        nullptr, nullptr, nullptr, xlb1, xrb1);
  k_gat1<<<(NN+3)/4, 256, 0, stream>>>(ro, ssrc, xlb1, xrb1, att1, bias1, h1);
  k_bnstats16<<<196, 256, 0, stream>>>(h1, stats1, D1, 256);

  // Layer 2: BN1+ELU fused into A-staging of gemm2
  k_gemm<D1, HD, true><<<dim3(MB, 1), 256, 0, stream>>>(h1, Wt2, b2l, b2r,
        stats1, gamma1, beta1, xlb2, xrb2);
  k_gat2<<<(NN+3)/4, 256, 0, stream>>>(ro, ssrc, xlb2, xrb2, att2, bias2, h2);
  k_bnstats<<<196, 256, 0, stream>>>(h2, stats2, HD, 256);

  // BN2 + ELU + pool (sorted-batch strip reduction), then MLP head
  {
    int waves = (NN + PW_NODES - 1)/PW_NODES;       // 2000
    int blocks = (waves + 3)/4;                      // 500
    k_bn2pool<<<blocks, 256, 0, stream>>>(h2, stats2, gamma2, beta2, batch, pool, pcnt);
  }
  k_mlp<<<NG, 64, 0, stream>>>(pool, pcnt, lw1, lb1, lw2, lb2, out);
}

// Round 16
// 384.929 us; speedup vs baseline: 1.3084x; 1.3084x over previous
//
#include <hip/hip_runtime.h>
#include <hip/hip_bf16.h>

#define NN 50000
#define NE 800000
#define ET (NE + NN)          // 850000 edges incl. self-loops
#define NG 64
#define IND 128
#define HD 64
#define NH 4
#define D1 256                // NH*HD
#define BN_EPS 1e-5f
#define SLOPE 0.2f
#define PW_NODES 25           // nodes per wave in k_bn2pool (2000 waves)
#define LOG2E 1.4426950408889634f

typedef unsigned short u16;
typedef __attribute__((ext_vector_type(8))) short bf16x8;
typedef __attribute__((ext_vector_type(4))) float f32x4;

__device__ __forceinline__ float b2f(u16 u){
  union { unsigned int i; float f; } c; c.i = ((unsigned int)u) << 16; return c.f;
}
__device__ __forceinline__ u16 f2b(float f){
  unsigned int u = __float_as_uint(f);
  u = (u + 0x7FFF + ((u >> 16) & 1)) >> 16;   // round-to-nearest-even
  return (u16)u;
}

// ---------------- mega-prep: casts + weight transposes + zeroing ----------------
#define PX   (NN*IND/4)            // 1,600,000  x -> bf16 (float4 chunks)
#define PW1  (2*D1*(IND/4))        // 16,384     Wt1
#define PW2  (2*HD*(D1/4))         // 8,192      Wt2
#define PZC  NN                    // 50,000     zero cur
#define PZS  (2*D1 + 2*HD + NG*HD + NG)  // 4,800 zero floats
#define PTOT (PX + PW1 + PW2 + PZC + PZS)

__global__ void k_prep(const float* __restrict__ x, u16* __restrict__ xb,
      const float* __restrict__ W1a, const float* __restrict__ W1b, u16* __restrict__ Wt1,
      const float* __restrict__ W2a, const float* __restrict__ W2b, u16* __restrict__ Wt2,
      int* __restrict__ cur, float* __restrict__ stats1, float* __restrict__ stats2,
      float* __restrict__ pool, float* __restrict__ pcnt){
  int id = blockIdx.x*256 + threadIdx.x;
  if (id < PX){
    float4 v = reinterpret_cast<const float4*>(x)[id];
    ushort4 o; o.x = f2b(v.x); o.y = f2b(v.y); o.z = f2b(v.z); o.w = f2b(v.w);
    reinterpret_cast<ushort4*>(xb)[id] = o;
    return;
  }
  id -= PX;
  if (id < PW1){
    int c  = id % (2*D1);
    int k4 = (id / (2*D1))*4;
    const float* W = (c < D1) ? W1a : W1b;
    int cl = (c < D1) ? c : c - D1;
    ushort4 o;
    o.x = f2b(W[(size_t)(k4+0)*D1 + cl]);
    o.y = f2b(W[(size_t)(k4+1)*D1 + cl]);
    o.z = f2b(W[(size_t)(k4+2)*D1 + cl]);
    o.w = f2b(W[(size_t)(k4+3)*D1 + cl]);
    *reinterpret_cast<ushort4*>(&Wt1[(size_t)c*IND + k4]) = o;
    return;
  }
  id -= PW1;
  if (id < PW2){
    int c  = id % (2*HD);
    int k4 = (id / (2*HD))*4;
    const float* W = (c < HD) ? W2a : W2b;
    int cl = (c < HD) ? c : c - HD;
    ushort4 o;
    o.x = f2b(W[(size_t)(k4+0)*HD + cl]);
    o.y = f2b(W[(size_t)(k4+1)*HD + cl]);
    o.z = f2b(W[(size_t)(k4+2)*HD + cl]);
    o.w = f2b(W[(size_t)(k4+3)*HD + cl]);
    *reinterpret_cast<ushort4*>(&Wt2[(size_t)c*D1 + k4]) = o;
    return;
  }
  id -= PW2;
  if (id < PZC){ cur[id] = 0; return; }
  id -= PZC;
  if (id < 2*D1){ stats1[id] = 0.f; return; }
  id -= 2*D1;
  if (id < 2*HD){ stats2[id] = 0.f; return; }
  id -= 2*HD;
  if (id < NG*HD){ pool[id] = 0.f; return; }
  id -= NG*HD;
  if (id < NG) pcnt[id] = 0.f;
}

// ---------------- CSR build (by dst) ----------------
__global__ void k_count(const int* __restrict__ ei, int* __restrict__ cnt){
  int e = blockIdx.x*256 + threadIdx.x;
  if (e >= ET) return;
  int d = (e < NE) ? ei[NE + e] : (e - NE);
  atomicAdd(&cnt[d], 1);
}

__global__ __launch_bounds__(1024) void k_scan1(const int* __restrict__ cnt,
                                                int* __restrict__ ro, int* __restrict__ part){
  __shared__ int s[1024];
  int i = blockIdx.x*1024 + threadIdx.x;
  int v = (i < NN) ? cnt[i] : 0;
  s[threadIdx.x] = v;
  __syncthreads();
  for (int off = 1; off < 1024; off <<= 1){
    int t = (threadIdx.x >= off) ? s[threadIdx.x - off] : 0;
    __syncthreads();
    s[threadIdx.x] += t;
    __syncthreads();
  }
  if (i < NN) ro[i] = s[threadIdx.x] - v;        // exclusive within block
  if (threadIdx.x == 1023) part[blockIdx.x] = s[1023];
}

__global__ __launch_bounds__(64) void k_scan2(int* __restrict__ part, int nb){
  __shared__ int s[64];
  int v = (threadIdx.x < nb) ? part[threadIdx.x] : 0;
  s[threadIdx.x] = v;
  __syncthreads();
  for (int off = 1; off < 64; off <<= 1){
    int t = (threadIdx.x >= off) ? s[threadIdx.x - off] : 0;
    __syncthreads();
    s[threadIdx.x] += t;
    __syncthreads();
  }
  if (threadIdx.x < nb) part[threadIdx.x] = s[threadIdx.x] - v;  // exclusive
}

// adds block offsets AND zeroes cur (dead after scan1) for scatter reuse
__global__ __launch_bounds__(1024) void k_scan3(const int* __restrict__ part, int* __restrict__ ro,
                                                int* __restrict__ cur){
  int i = blockIdx.x*1024 + threadIdx.x;
  if (i < NN){ ro[i] += part[blockIdx.x]; cur[i] = 0; }
  if (i == 0) ro[NN] = ET;
}

__global__ void k_scatter(const int* __restrict__ ei, const int* __restrict__ ro,
                          int* __restrict__ cur, int* __restrict__ ssrc){
  int e = blockIdx.x*256 + threadIdx.x;
  if (e >= ET) return;
  int s, d;
  if (e < NE){ s = ei[e]; d = ei[NE + e]; } else { s = e - NE; d = s; }
  int pos = ro[d] + atomicAdd(&cur[d], 1);
  ssrc[pos] = s;
}

// ---------------- MFMA dual GEMM (bf16 in, bf16 out); optional fused BN+ELU on A ----------------
template<int KT, int NOUT, bool BN>
__global__ __launch_bounds__(256) void k_gemm(const u16* __restrict__ Ab,
      const u16* __restrict__ Wt, const float* __restrict__ ba, const float* __restrict__ bb,
      const float* __restrict__ stats, const float* __restrict__ gamma, const float* __restrict__ beta,
      u16* __restrict__ Ca, u16* __restrict__ Cb){
  __shared__ u16 As[64][32];
  __shared__ u16 Bs[128][32];
  __shared__ float scl[KT];
  __shared__ float shl[KT];
  int t = threadIdx.x;
  int lane = t & 63;
  int w = t >> 6;
  int wm = w >> 1, wn = w & 1;
  int n0 = blockIdx.x*64;
  int cb0 = blockIdx.y*128;

  if constexpr (BN){
    for (int c = t; c < KT; c += 256){
      float mu = stats[c]*(1.f/NN);
      float var = stats[KT + c]*(1.f/NN) - mu*mu;
      float g = gamma[c]*rsqrtf(var + BN_EPS);
      scl[c] = g;
      shl[c] = beta[c] - mu*g;
    }
    __syncthreads();
  }

  f32x4 acc[2][4];
  #pragma unroll
  for (int i = 0; i < 2; i++)
    #pragma unroll
    for (int j = 0; j < 4; j++) acc[i][j] = (f32x4){0.f,0.f,0.f,0.f};

  int sr = t >> 3;          // staging row/col 0..31
  int k4 = (t & 7)*4;       // staging k chunk
  int fm = lane & 15;       // fragment row/col
  int fk = (lane >> 4)*8;   // fragment k base

  for (int kb = 0; kb < KT/32; kb++){
    int kbase = kb*32;
    #pragma unroll
    for (int p = 0; p < 2; p++){
      int r = sr + p*32;
      int gn = n0 + r;
      ushort4 v = make_ushort4(0,0,0,0);
      if (gn < NN) v = *reinterpret_cast<const ushort4*>(&Ab[(size_t)gn*KT + kbase + k4]);
      if constexpr (BN){
        int c0 = kbase + k4;
        float f0 = b2f(v.x)*scl[c0+0] + shl[c0+0]; f0 = (f0 > 0.f) ? f0 : (__expf(f0) - 1.f);
        float f1 = b2f(v.y)*scl[c0+1] + shl[c0+1]; f1 = (f1 > 0.f) ? f1 : (__expf(f1) - 1.f);
        float f2 = b2f(v.z)*scl[c0+2] + shl[c0+2]; f2 = (f2 > 0.f) ? f2 : (__expf(f2) - 1.f);
        float f3 = b2f(v.w)*scl[c0+3] + shl[c0+3]; f3 = (f3 > 0.f) ? f3 : (__expf(f3) - 1.f);
        v.x = f2b(f0); v.y = f2b(f1); v.z = f2b(f2); v.w = f2b(f3);
      }
      *reinterpret_cast<ushort4*>(&As[r][k4]) = v;
    }
    #pragma unroll
    for (int q = 0; q < 4; q++){
      int cn = sr + q*32;
      ushort4 v = *reinterpret_cast<const ushort4*>(&Wt[(size_t)(cb0+cn)*KT + kbase + k4]);
      *reinterpret_cast<ushort4*>(&Bs[cn][k4]) = v;
    }
    __syncthreads();
    bf16x8 af0 = *reinterpret_cast<const bf16x8*>(&As[wm*32 + fm][fk]);
    bf16x8 af1 = *reinterpret_cast<const bf16x8*>(&As[wm*32 + 16 + fm][fk]);
    #pragma unroll
    for (int nt = 0; nt < 4; nt++){
      bf16x8 bfr = *reinterpret_cast<const bf16x8*>(&Bs[wn*64 + nt*16 + fm][fk]);
      acc[0][nt] = __builtin_amdgcn_mfma_f32_16x16x32_bf16(af0, bfr, acc[0][nt], 0, 0, 0);
      acc[1][nt] = __builtin_amdgcn_mfma_f32_16x16x32_bf16(af1, bfr, acc[1][nt], 0, 0, 0);
    }
    __syncthreads();
  }

  // epilogue: C/D layout col=lane&15, row=(lane>>4)*4+reg  [m89-verified]
  int frow = (lane >> 4)*4;
  #pragma unroll
  for (int nt = 0; nt < 4; nt++){
    int cn = cb0 + wn*64 + nt*16 + fm;
    bool first = (cn < NOUT);
    int cl = first ? cn : cn - NOUT;
    float bv = first ? ba[cl] : bb[cl];
    u16* Cp = first ? Ca : Cb;
    #pragma unroll
    for (int mt = 0; mt < 2; mt++){
      #pragma unroll
      for (int r = 0; r < 4; r++){
        int grow = n0 + wm*32 + mt*16 + frow + r;
        if (grow < NN) Cp[(size_t)grow*NOUT + cl] = f2b(acc[mt][nt][r] + bv);
      }
    }
  }
}

// ---- Fused GATv2 layer 1: 4x edge unroll; bf16 output ----
__global__ __launch_bounds__(256) void k_gat1(const int* __restrict__ ro, const int* __restrict__ ssrc,
      const u16* __restrict__ xl, const u16* __restrict__ xr,
      const float* __restrict__ att, const float* __restrict__ bias,
      u16* __restrict__ out){
  int widx = threadIdx.x >> 6, lane = threadIdx.x & 63;
  int n = blockIdx.x*4 + widx;
  if (n >= NN) return;
  int base = (lane >> 4)*HD + (lane & 15)*4;
  ushort4 ur = *reinterpret_cast<const ushort4*>(&xr[(size_t)n*D1 + base]);
  float xr0 = b2f(ur.x), xr1 = b2f(ur.y), xr2 = b2f(ur.z), xr3 = b2f(ur.w);
  float4 at4 = *reinterpret_cast<const float4*>(&att[base]);
  float a1x = 0.6f*LOG2E*at4.x, a2x = 0.4f*LOG2E*at4.x;
  float a1y = 0.6f*LOG2E*at4.y, a2y = 0.4f*LOG2E*at4.y;
  float a1z = 0.6f*LOG2E*at4.z, a2z = 0.4f*LOG2E*at4.z;
  float a1w = 0.6f*LOG2E*at4.w, a2w = 0.4f*LOG2E*at4.w;
  float m = -1e30f, den = 0.f;
  float ax=0.f, ay=0.f, az=0.f, aw=0.f;
  int b = ro[n], e = ro[n+1];
  int i = b;
  for (; i + 3 < e; i += 4){
    int s0 = ssrc[i], s1 = ssrc[i+1], s2 = ssrc[i+2], s3 = ssrc[i+3];
    ushort4 u0 = *reinterpret_cast<const ushort4*>(&xl[(size_t)s0*D1 + base]);
    ushort4 u1 = *reinterpret_cast<const ushort4*>(&xl[(size_t)s1*D1 + base]);
    ushort4 u2 = *reinterpret_cast<const ushort4*>(&xl[(size_t)s2*D1 + base]);
    ushort4 u3 = *reinterpret_cast<const ushort4*>(&xl[(size_t)s3*D1 + base]);
    float v0x=b2f(u0.x), v0y=b2f(u0.y), v0z=b2f(u0.z), v0w=b2f(u0.w);
    float v1x=b2f(u1.x), v1y=b2f(u1.y), v1z=b2f(u1.z), v1w=b2f(u1.w);
    float v2x=b2f(u2.x), v2y=b2f(u2.y), v2z=b2f(u2.z), v2w=b2f(u2.w);
    float v3x=b2f(u3.x), v3y=b2f(u3.y), v3z=b2f(u3.z), v3w=b2f(u3.w);
    float t0, t1, t2, t3;
    float L0, L1, L2, L3;
    t0 = v0x+xr0; t1 = v0y+xr1; t2 = v0z+xr2; t3 = v0w+xr3;
    L0 = fmaf(a1x,t0, a2x*fabsf(t0));
    L0 = fmaf(a1y,t1, fmaf(a2y,fabsf(t1), L0));
    L0 = fmaf(a1z,t2, fmaf(a2z,fabsf(t2), L0));
    L0 = fmaf(a1w,t3, fmaf(a2w,fabsf(t3), L0));
    t0 = v1x+xr0; t1 = v1y+xr1; t2 = v1z+xr2; t3 = v1w+xr3;
    L1 = fmaf(a1x,t0, a2x*fabsf(t0));
    L1 = fmaf(a1y,t1, fmaf(a2y,fabsf(t1), L1));
    L1 = fmaf(a1z,t2, fmaf(a2z,fabsf(t2), L1));
    L1 = fmaf(a1w,t3, fmaf(a2w,fabsf(t3), L1));
    t0 = v2x+xr0; t1 = v2y+xr1; t2 = v2z+xr2; t3 = v2w+xr3;
    L2 = fmaf(a1x,t0, a2x*fabsf(t0));
    L2 = fmaf(a1y,t1, fmaf(a2y,fabsf(t1), L2));
    L2 = fmaf(a1z,t2, fmaf(a2z,fabsf(t2), L2));
    L2 = fmaf(a1w,t3, fmaf(a2w,fabsf(t3), L2));
    t0 = v3x+xr0; t1 = v3y+xr1; t2 = v3z+xr2; t3 = v3w+xr3;
    L3 = fmaf(a1x,t0, a2x*fabsf(t0));
    L3 = fmaf(a1y,t1, fmaf(a2y,fabsf(t1), L3));
    L3 = fmaf(a1z,t2, fmaf(a2z,fabsf(t2), L3));
    L3 = fmaf(a1w,t3, fmaf(a2w,fabsf(t3), L3));
    #pragma unroll
    for (int off = 1; off <= 8; off <<= 1){
      L0 += __shfl_xor(L0, off); L1 += __shfl_xor(L1, off);
      L2 += __shfl_xor(L2, off); L3 += __shfl_xor(L3, off);
    }
    float Lm = fmaxf(fmaxf(L0, L1), fmaxf(L2, L3));
    if (__any(Lm > m + 8.f)){
      float mn = fmaxf(m, Lm);
      float corr = exp2f(m - mn);
      den *= corr; ax *= corr; ay *= corr; az *= corr; aw *= corr;
      m = mn;
    }
    float p0 = exp2f(L0 - m), p1 = exp2f(L1 - m);
    float p2 = exp2f(L2 - m), p3 = exp2f(L3 - m);
    den += (p0 + p1) + (p2 + p3);
    ax = fmaf(p0,v0x, fmaf(p1,v1x, fmaf(p2,v2x, fmaf(p3,v3x, ax))));
    ay = fmaf(p0,v0y, fmaf(p1,v1y, fmaf(p2,v2y, fmaf(p3,v3y, ay))));
    az = fmaf(p0,v0z, fmaf(p1,v1z, fmaf(p2,v2z, fmaf(p3,v3z, az))));
    aw = fmaf(p0,v0w, fmaf(p1,v1w, fmaf(p2,v2w, fmaf(p3,v3w, aw))));
  }
  for (; i < e; i++){
    int s = ssrc[i];
    ushort4 u = *reinterpret_cast<const ushort4*>(&xl[(size_t)s*D1 + base]);
    float vx = b2f(u.x), vy = b2f(u.y), vz = b2f(u.z), vw = b2f(u.w);
    float t0 = vx + xr0, t1 = vy + xr1, t2 = vz + xr2, t3 = vw + xr3;
    float L;
    L = fmaf(a1x, t0, a2x*fabsf(t0));
    L = fmaf(a1y, t1, fmaf(a2y, fabsf(t1), L));
    L = fmaf(a1z, t2, fmaf(a2z, fabsf(t2), L));
    L = fmaf(a1w, t3, fmaf(a2w, fabsf(t3), L));
    L += __shfl_xor(L, 1); L += __shfl_xor(L, 2);
    L += __shfl_xor(L, 4); L += __shfl_xor(L, 8);
    if (__any(L > m + 8.f)){
      float mn = fmaxf(m, L);
      float corr = exp2f(m - mn);
      den *= corr; ax *= corr; ay *= corr; az *= corr; aw *= corr;
      m = mn;
    }
    float p = exp2f(L - m);
    den += p;
    ax = fmaf(p, vx, ax);
    ay = fmaf(p, vy, ay);
    az = fmaf(p, vz, az);
    aw = fmaf(p, vw, aw);
  }
  float inv = 1.f/den;
  float4 b4 = *reinterpret_cast<const float4*>(&bias[base]);
  ushort4 o;
  o.x = f2b(ax*inv + b4.x); o.y = f2b(ay*inv + b4.y);
  o.z = f2b(az*inv + b4.z); o.w = f2b(aw*inv + b4.w);
  *reinterpret_cast<ushort4*>(&out[(size_t)n*D1 + base]) = o;
}

// ---------------- BatchNorm stats ----------------
__global__ __launch_bounds__(256) void k_bnstats16(const u16* __restrict__ h, float* __restrict__ stats,
                                                   int ncols, int rpb){
  int nrl = 256/ncols;
  int c = threadIdx.x % ncols;
  int rl = threadIdx.x / ncols;
  int r0 = blockIdx.x*rpb + rl;
  int r1 = min(NN, (blockIdx.x+1)*rpb);
  float s = 0.f, s2 = 0.f;
  for (int r = r0; r < r1; r += nrl){
    float v = b2f(h[(size_t)r*ncols + c]);
    s += v; s2 += v*v;
  }
  atomicAdd(&stats[c], s);
  atomicAdd(&stats[ncols + c], s2);
}

__global__ __launch_bounds__(256) void k_bnstats(const float* __restrict__ h, float* __restrict__ stats,
                                                 int ncols, int rpb){
  int nrl = 256/ncols;
  int c = threadIdx.x % ncols;
  int rl = threadIdx.x / ncols;
  int r0 = blockIdx.x*rpb + rl;
  int r1 = min(NN, (blockIdx.x+1)*rpb);
  float s = 0.f, s2 = 0.f;
  for (int r = r0; r < r1; r += nrl){
    float v = h[(size_t)r*ncols + c];
    s += v; s2 += v*v;
  }
  atomicAdd(&stats[c], s);
  atomicAdd(&stats[ncols + c], s2);
}

// ---- Fused GATv2 layer 2 (1 head): 4 lane-groups, 2x unroll ----
__global__ __launch_bounds__(256) void k_gat2(const int* __restrict__ ro, const int* __restrict__ ssrc,
      const u16* __restrict__ xl, const u16* __restrict__ xr,
      const float* __restrict__ att, const float* __restrict__ bias,
      float* __restrict__ out){
  int widx = threadIdx.x >> 6, lane = threadIdx.x & 63;
  int n = blockIdx.x*4 + widx;
  if (n >= NN) return;
  int g = lane >> 4, c4 = (lane & 15)*4;
  ushort4 ur = *reinterpret_cast<const ushort4*>(&xr[(size_t)n*HD + c4]);
  float xr0 = b2f(ur.x), xr1 = b2f(ur.y), xr2 = b2f(ur.z), xr3 = b2f(ur.w);
  float4 at4 = *reinterpret_cast<const float4*>(&att[c4]);
  float a1x = 0.6f*LOG2E*at4.x, a2x = 0.4f*LOG2E*at4.x;
  float a1y = 0.6f*LOG2E*at4.y, a2y = 0.4f*LOG2E*at4.y;
  float a1z = 0.6f*LOG2E*at4.z, a2z = 0.4f*LOG2E*at4.z;
  float a1w = 0.6f*LOG2E*at4.w, a2w = 0.4f*LOG2E*at4.w;
  float m = -1e30f, den = 0.f;
  float ax=0.f, ay=0.f, az=0.f, aw=0.f;
  int b = ro[n], e = ro[n+1];
  int i = b + g;
  for (; i + 4 < e; i += 8){
    int s0 = ssrc[i], s1 = ssrc[i+4];
    ushort4 u0 = *reinterpret_cast<const ushort4*>(&xl[(size_t)s0*HD + c4]);
    ushort4 u1 = *reinterpret_cast<const ushort4*>(&xl[(size_t)s1*HD + c4]);
    float v0x=b2f(u0.x), v0y=b2f(u0.y), v0z=b2f(u0.z), v0w=b2f(u0.w);
    float v1x=b2f(u1.x), v1y=b2f(u1.y), v1z=b2f(u1.z), v1w=b2f(u1.w);
    float t0, t1, t2, t3, L0, L1;
    t0 = v0x+xr0; t1 = v0y+xr1; t2 = v0z+xr2; t3 = v0w+xr3;
    L0 = fmaf(a1x,t0, a2x*fabsf(t0));
    L0 = fmaf(a1y,t1, fmaf(a2y,fabsf(t1), L0));
    L0 = fmaf(a1z,t2, fmaf(a2z,fabsf(t2), L0));
    L0 = fmaf(a1w,t3, fmaf(a2w,fabsf(t3), L0));
    t0 = v1x+xr0; t1 = v1y+xr1; t2 = v1z+xr2; t3 = v1w+xr3;
    L1 = fmaf(a1x,t0, a2x*fabsf(t0));
    L1 = fmaf(a1y,t1, fmaf(a2y,fabsf(t1), L1));
    L1 = fmaf(a1z,t2, fmaf(a2z,fabsf(t2), L1));
    L1 = fmaf(a1w,t3, fmaf(a2w,fabsf(t3), L1));
    #pragma unroll
    for (int off = 1; off <= 8; off <<= 1){
      L0 += __shfl_xor(L0, off); L1 += __shfl_xor(L1, off);
    }
    float Lm = fmaxf(L0, L1);
    if (__any(Lm > m + 8.f)){
      float mn = fmaxf(m, Lm);
      float corr = exp2f(m - mn);
      den *= corr; ax *= corr; ay *= corr; az *= corr; aw *= corr;
      m = mn;
    }
    float p0 = exp2f(L0 - m), p1 = exp2f(L1 - m);
    den += p0 + p1;
    ax = fmaf(p0, v0x, fmaf(p1, v1x, ax));
    ay = fmaf(p0, v0y, fmaf(p1, v1y, ay));
    az = fmaf(p0, v0z, fmaf(p1, v1z, az));
    aw = fmaf(p0, v0w, fmaf(p1, v1w, aw));
  }
  for (; i < e; i += 4){
    int s = ssrc[i];
    ushort4 u = *reinterpret_cast<const ushort4*>(&xl[(size_t)s*HD + c4]);
    float vx = b2f(u.x), vy = b2f(u.y), vz = b2f(u.z), vw = b2f(u.w);
    float t0 = vx + xr0, t1 = vy + xr1, t2 = vz + xr2, t3 = vw + xr3;
    float L;
    L = fmaf(a1x, t0, a2x*fabsf(t0));
    L = fmaf(a1y, t1, fmaf(a2y, fabsf(t1), L));
    L = fmaf(a1z, t2, fmaf(a2z, fabsf(t2), L));
    L = fmaf(a1w, t3, fmaf(a2w, fabsf(t3), L));
    L += __shfl_xor(L, 1); L += __shfl_xor(L, 2);
    L += __shfl_xor(L, 4); L += __shfl_xor(L, 8);
    if (__any(L > m + 8.f)){
      float mn = fmaxf(m, L);
      float corr = exp2f(m - mn);
      den *= corr; ax *= corr; ay *= corr; az *= corr; aw *= corr;
      m = mn;
    }
    float p = exp2f(L - m);
    den += p;
    ax = fmaf(p, vx, ax);
    ay = fmaf(p, vy, ay);
    az = fmaf(p, vz, az);
    aw = fmaf(p, vw, aw);
  }
  // exact merge of the 4 per-group partials (lanes l^16 / l^32 share c4)
  #pragma unroll
  for (int off = 16; off <= 32; off <<= 1){
    float mo  = __shfl_xor(m, off);
    float dno = __shfl_xor(den, off);
    float bx  = __shfl_xor(ax, off);
    float by  = __shfl_xor(ay, off);
    float bz  = __shfl_xor(az, off);
    float bw  = __shfl_xor(aw, off);
    float mn = fmaxf(m, mo);
    float c1 = exp2f(m - mn), c2 = exp2f(mo - mn);
    den = den*c1 + dno*c2;
    ax = ax*c1 + bx*c2;
    ay = ay*c1 + by*c2;
    az = az*c1 + bz*c2;
    aw = aw*c1 + bw*c2;
    m = mn;
  }
  float inv = 1.f/den;
  float4 b4 = *reinterpret_cast<const float4*>(&bias[c4]);
  float4 o = make_float4(ax*inv + b4.x, ay*inv + b4.y, az*inv + b4.z, aw*inv + b4.w);
  *reinterpret_cast<float4*>(&out[(size_t)n*HD + c4]) = o;
}

// BN2 + ELU + pooled sums, sorted-batch strip reduction (25 nodes/wave)
__global__ __launch_bounds__(256) void k_bn2pool(const float* __restrict__ h2, const float* __restrict__ stats,
      const float* __restrict__ gamma, const float* __restrict__ beta,
      const int* __restrict__ batch, float* __restrict__ pool, float* __restrict__ pcnt){
  int wave = blockIdx.x*4 + (threadIdx.x >> 6);
  int lane = threadIdx.x & 63;
  int n0 = wave*PW_NODES;
  if (n0 >= NN) return;
  int n1 = min(NN, n0 + PW_NODES);
  const float invn = 1.f/NN;
  float mu = stats[lane]*invn;
  float var = stats[HD + lane]*invn - mu*mu;
  float sc = gamma[lane]*rsqrtf(var + BN_EPS);
  float sh = beta[lane] - mu*sc;
  int curg = batch[n0];
  float acc = 0.f, cnt = 0.f;
  for (int n = n0; n < n1; n++){
    int g = batch[n];
    if (g != curg){
      atomicAdd(&pool[curg*HD + lane], acc);
      if (lane == 0) atomicAdd(&pcnt[curg], cnt);
      acc = 0.f; cnt = 0.f; curg = g;
    }
    float v = h2[(size_t)n*HD + lane]*sc + sh;
    v = (v > 0.f) ? v : (__expf(v) - 1.f);
    acc += v; cnt += 1.f;
  }
  atomicAdd(&pool[curg*HD + lane], acc);
  if (lane == 0) atomicAdd(&pcnt[curg], cnt);
}

// final MLP: out[g] = elu(pooled@lw1+lb1) @ lw2 + lb2   (f32 output)
__global__ __launch_bounds__(64) void k_mlp(const float* __restrict__ pool, const float* __restrict__ pcnt,
      const float* __restrict__ lw1, const float* __restrict__ lb1,
      const float* __restrict__ lw2, const float* __restrict__ lb2, float* __restrict__ out){
  __shared__ float p[HD];
  int g = blockIdx.x, c = threadIdx.x;
  float cnt = fmaxf(pcnt[g], 1.f);
  p[c] = pool[g*HD + c]/cnt;
  __syncthreads();
  float acc = lb1[c];
  for (int k = 0; k < HD; k++) acc += p[k]*lw1[k*HD + c];
  acc = (acc > 0.f) ? acc : (__expf(acc) - 1.f);
  float t = acc * lw2[c];
  #pragma unroll
  for (int off = 32; off > 0; off >>= 1) t += __shfl_xor(t, off, 64);
  if (c == 0) out[g] = t + lb2[0];
}

extern "C" void kernel_launch(void* const* d_in, const int* in_sizes, int n_in,
                              void* d_out, int out_size, void* d_ws, size_t ws_size,
                              hipStream_t stream){
  const float* x    = (const float*)d_in[0];
  const int*  ei    = (const int*) d_in[1];
  const int*  batch = (const int*) d_in[2];
  const float* W1l = (const float*)d_in[3];
  const float* b1l = (const float*)d_in[4];
  const float* W1r = (const float*)d_in[5];
  const float* b1r = (const float*)d_in[6];
  const float* att1= (const float*)d_in[7];
  const float* bias1=(const float*)d_in[8];
  const float* gamma1=(const float*)d_in[9];
  const float* beta1 =(const float*)d_in[10];
  const float* W2l = (const float*)d_in[11];
  const float* b2l = (const float*)d_in[12];
  const float* W2r = (const float*)d_in[13];
  const float* b2r = (const float*)d_in[14];
  const float* att2= (const float*)d_in[15];
  const float* bias2=(const float*)d_in[16];
  const float* gamma2=(const float*)d_in[17];
  const float* beta2 =(const float*)d_in[18];
  const float* lw1 = (const float*)d_in[19];
  const float* lb1 = (const float*)d_in[20];
  const float* lw2 = (const float*)d_in[21];
  const float* lb2 = (const float*)d_in[22];
  float* out = (float*)d_out;

  char* w = (char*)d_ws;
  size_t off = 0;
  auto take = [&](size_t bytes)->char*{
    char* p = w + off;
    off = (off + bytes + 255) & ~(size_t)255;
    return p;
  };
  int*   ro    = (int*)  take((NN+1)*sizeof(int));
  int*   cur   = (int*)  take((size_t)NN*sizeof(int));
  int*   ssrc  = (int*)  take((size_t)ET*sizeof(int));
  int*   part  = (int*)  take(64*sizeof(int));
  float* stats1= (float*)take(2*D1*sizeof(float));
  float* stats2= (float*)take(2*HD*sizeof(float));
  float* pool  = (float*)take(NG*HD*sizeof(float));
  float* pcnt  = (float*)take(NG*sizeof(float));
  u16*   xb    = (u16*)  take((size_t)NN*IND*sizeof(u16));
  u16*   Wt1   = (u16*)  take((size_t)2*D1*IND*sizeof(u16));   // [512][128]
  u16*   Wt2   = (u16*)  take((size_t)2*HD*D1*sizeof(u16));    // [128][256]
  char*  bufA  = take((size_t)NN*D1*2*sizeof(u16));            // xlb1+xrb1; later xlb2+xrb2+h2
  u16*   h1    = (u16*)  take((size_t)NN*D1*sizeof(u16));      // bf16 h1 (raw, pre-BN)

  u16* xlb1 = (u16*)bufA;
  u16* xrb1 = xlb1 + (size_t)NN*D1;
  u16* xlb2 = (u16*)bufA;                                      // overlays dead xlb1
  u16* xrb2 = xlb2 + (size_t)NN*HD;
  float* h2 = (float*)(bufA + (size_t)2*NN*HD*sizeof(u16));

  // mega-prep: casts + weight transposes + zero cur/stats/pool/pcnt
  k_prep<<<(PTOT + 255)/256, 256, 0, stream>>>(x, xb, W1l, W1r, Wt1, W2l, W2r, Wt2,
                                               cur, stats1, stats2, pool, pcnt);

  // CSR build: count -> 3-kernel scan (scan3 re-zeroes cur) -> scatter
  k_count<<<(ET+255)/256, 256, 0, stream>>>(ei, cur);
  int nsb = (NN + 1023)/1024;                       // 49 blocks
  k_scan1<<<nsb, 1024, 0, stream>>>(cur, ro, part);
  k_scan2<<<1, 64, 0, stream>>>(part, nsb);
  k_scan3<<<nsb, 1024, 0, stream>>>(part, ro, cur);
  k_scatter<<<(ET+255)/256, 256, 0, stream>>>(ei, ro, cur, ssrc);

  const int MB = (NN + 63)/64;                      // 782 row tiles

  // Layer 1: MFMA dual GEMM (bf16) then fused gather+softmax+aggregate
  k_gemm<IND, D1, false><<<dim3(MB, 4), 256, 0, stream>>>(xb, Wt1, b1l, b1r,
        nullptr, nullptr, nullptr, xlb1, xrb1);
  k_gat1<<<(NN+3)/4, 256, 0, stream>>>(ro, ssrc, xlb1, xrb1, att1, bias1, h1);
  k_bnstats16<<<196, 256, 0, stream>>>(h1, stats1, D1, 256);

  // Layer 2: BN1+ELU fused into A-staging of gemm2
  k_gemm<D1, HD, true><<<dim3(MB, 1), 256, 0, stream>>>(h1, Wt2, b2l, b2r,
        stats1, gamma1, beta1, xlb2, xrb2);
  k_gat2<<<(NN+3)/4, 256, 0, stream>>>(ro, ssrc, xlb2, xrb2, att2, bias2, h2);
  k_bnstats<<<196, 256, 0, stream>>>(h2, stats2, HD, 256);

  // BN2 + ELU + pool (sorted-batch strip reduction), then MLP head
  {
    int waves = (NN + PW_NODES - 1)/PW_NODES;       // 2000
    int blocks = (waves + 3)/4;                      // 500
    k_bn2pool<<<blocks, 256, 0, stream>>>(h2, stats2, gamma2, beta2, batch, pool, pcnt);
  }
  k_mlp<<<NG, 64, 0, stream>>>(pool, pcnt, lw1, lb1, lw2, lb2, out);
}

// Round 17
// 375.843 us; speedup vs baseline: 1.3400x; 1.0242x over previous
//
#include <hip/hip_runtime.h>
#include <hip/hip_bf16.h>

#define NN 50000
#define NE 800000
#define ET (NE + NN)          // 850000 edges incl. self-loops
#define NG 64
#define IND 128
#define HD 64
#define NH 4
#define D1 256                // NH*HD
#define BN_EPS 1e-5f
#define SLOPE 0.2f
#define PW_NODES 25           // nodes per wave in k_bn2pool (2000 waves)
#define LOG2E 1.4426950408889634f

typedef unsigned short u16;
typedef __attribute__((ext_vector_type(8))) short bf16x8;
typedef __attribute__((ext_vector_type(4))) float f32x4;

__device__ __forceinline__ float b2f(u16 u){
  union { unsigned int i; float f; } c; c.i = ((unsigned int)u) << 16; return c.f;
}
__device__ __forceinline__ u16 f2b(float f){
  unsigned int u = __float_as_uint(f);
  u = (u + 0x7FFF + ((u >> 16) & 1)) >> 16;   // round-to-nearest-even
  return (u16)u;
}
// 16-lane sum via DPP row-rotate (VALU-only; replaces ds_swizzle butterfly)
__device__ __forceinline__ float rsum16(float x){
  x += __int_as_float(__builtin_amdgcn_update_dpp(0, __float_as_int(x), 0x121, 0xf, 0xf, false));
  x += __int_as_float(__builtin_amdgcn_update_dpp(0, __float_as_int(x), 0x122, 0xf, 0xf, false));
  x += __int_as_float(__builtin_amdgcn_update_dpp(0, __float_as_int(x), 0x124, 0xf, 0xf, false));
  x += __int_as_float(__builtin_amdgcn_update_dpp(0, __float_as_int(x), 0x128, 0xf, 0xf, false));
  return x;
}

// ---------------- mega-prep: casts + weight transposes + zeroing ----------------
#define PX   (NN*IND/4)            // 1,600,000  x -> bf16 (float4 chunks)
#define PW1  (2*D1*(IND/4))        // 16,384     Wt1
#define PW2  (2*HD*(D1/4))         // 8,192      Wt2
#define PZC  NN                    // 50,000     zero cur
#define PZS  (2*D1 + 2*HD + NG*HD + NG)  // 4,800 zero floats
#define PTOT (PX + PW1 + PW2 + PZC + PZS)

__global__ void k_prep(const float* __restrict__ x, u16* __restrict__ xb,
      const float* __restrict__ W1a, const float* __restrict__ W1b, u16* __restrict__ Wt1,
      const float* __restrict__ W2a, const float* __restrict__ W2b, u16* __restrict__ Wt2,
      int* __restrict__ cur, float* __restrict__ stats1, float* __restrict__ stats2,
      float* __restrict__ pool, float* __restrict__ pcnt){
  int id = blockIdx.x*256 + threadIdx.x;
  if (id < PX){
    float4 v = reinterpret_cast<const float4*>(x)[id];
    ushort4 o; o.x = f2b(v.x); o.y = f2b(v.y); o.z = f2b(v.z); o.w = f2b(v.w);
    reinterpret_cast<ushort4*>(xb)[id] = o;
    return;
  }
  id -= PX;
  if (id < PW1){
    int c  = id % (2*D1);
    int k4 = (id / (2*D1))*4;
    const float* W = (c < D1) ? W1a : W1b;
    int cl = (c < D1) ? c : c - D1;
    ushort4 o;
    o.x = f2b(W[(size_t)(k4+0)*D1 + cl]);
    o.y = f2b(W[(size_t)(k4+1)*D1 + cl]);
    o.z = f2b(W[(size_t)(k4+2)*D1 + cl]);
    o.w = f2b(W[(size_t)(k4+3)*D1 + cl]);
    *reinterpret_cast<ushort4*>(&Wt1[(size_t)c*IND + k4]) = o;
    return;
  }
  id -= PW1;
  if (id < PW2){
    int c  = id % (2*HD);
    int k4 = (id / (2*HD))*4;
    const float* W = (c < HD) ? W2a : W2b;
    int cl = (c < HD) ? c : c - HD;
    ushort4 o;
    o.x = f2b(W[(size_t)(k4+0)*HD + cl]);
    o.y = f2b(W[(size_t)(k4+1)*HD + cl]);
    o.z = f2b(W[(size_t)(k4+2)*HD + cl]);
    o.w = f2b(W[(size_t)(k4+3)*HD + cl]);
    *reinterpret_cast<ushort4*>(&Wt2[(size_t)c*D1 + k4]) = o;
    return;
  }
  id -= PW2;
  if (id < PZC){ cur[id] = 0; return; }
  id -= PZC;
  if (id < 2*D1){ stats1[id] = 0.f; return; }
  id -= 2*D1;
  if (id < 2*HD){ stats2[id] = 0.f; return; }
  id -= 2*HD;
  if (id < NG*HD){ pool[id] = 0.f; return; }
  id -= NG*HD;
  if (id < NG) pcnt[id] = 0.f;
}

// ---------------- CSR build (by dst) ----------------
__global__ void k_count(const int* __restrict__ ei, int* __restrict__ cnt){
  int e = blockIdx.x*256 + threadIdx.x;
  if (e >= ET) return;
  int d = (e < NE) ? ei[NE + e] : (e - NE);
  atomicAdd(&cnt[d], 1);
}

__global__ __launch_bounds__(1024) void k_scan1(const int* __restrict__ cnt,
                                                int* __restrict__ ro, int* __restrict__ part){
  __shared__ int s[1024];
  int i = blockIdx.x*1024 + threadIdx.x;
  int v = (i < NN) ? cnt[i] : 0;
  s[threadIdx.x] = v;
  __syncthreads();
  for (int off = 1; off < 1024; off <<= 1){
    int t = (threadIdx.x >= off) ? s[threadIdx.x - off] : 0;
    __syncthreads();
    s[threadIdx.x] += t;
    __syncthreads();
  }
  if (i < NN) ro[i] = s[threadIdx.x] - v;        // exclusive within block
  if (threadIdx.x == 1023) part[blockIdx.x] = s[1023];
}

__global__ __launch_bounds__(64) void k_scan2(int* __restrict__ part, int nb){
  __shared__ int s[64];
  int v = (threadIdx.x < nb) ? part[threadIdx.x] : 0;
  s[threadIdx.x] = v;
  __syncthreads();
  for (int off = 1; off < 64; off <<= 1){
    int t = (threadIdx.x >= off) ? s[threadIdx.x - off] : 0;
    __syncthreads();
    s[threadIdx.x] += t;
    __syncthreads();
  }
  if (threadIdx.x < nb) part[threadIdx.x] = s[threadIdx.x] - v;  // exclusive
}

// adds block offsets AND zeroes cur (dead after scan1) for scatter reuse
__global__ __launch_bounds__(1024) void k_scan3(const int* __restrict__ part, int* __restrict__ ro,
                                                int* __restrict__ cur){
  int i = blockIdx.x*1024 + threadIdx.x;
  if (i < NN){ ro[i] += part[blockIdx.x]; cur[i] = 0; }
  if (i == 0) ro[NN] = ET;
}

__global__ void k_scatter(const int* __restrict__ ei, const int* __restrict__ ro,
                          int* __restrict__ cur, int* __restrict__ ssrc){
  int e = blockIdx.x*256 + threadIdx.x;
  if (e >= ET) return;
  int s, d;
  if (e < NE){ s = ei[e]; d = ei[NE + e]; } else { s = e - NE; d = s; }
  int pos = ro[d] + atomicAdd(&cur[d], 1);
  ssrc[pos] = s;
}

// ---------------- MFMA dual GEMM (bf16 in, bf16 out); optional fused BN+ELU on A ----------------
template<int KT, int NOUT, bool BN>
__global__ __launch_bounds__(256) void k_gemm(const u16* __restrict__ Ab,
      const u16* __restrict__ Wt, const float* __restrict__ ba, const float* __restrict__ bb,
      const float* __restrict__ stats, const float* __restrict__ gamma, const float* __restrict__ beta,
      u16* __restrict__ Ca, u16* __restrict__ Cb){
  __shared__ u16 As[64][32];
  __shared__ u16 Bs[128][32];
  __shared__ float scl[KT];
  __shared__ float shl[KT];
  int t = threadIdx.x;
  int lane = t & 63;
  int w = t >> 6;
  int wm = w >> 1, wn = w & 1;
  int n0 = blockIdx.x*64;
  int cb0 = blockIdx.y*128;

  if constexpr (BN){
    for (int c = t; c < KT; c += 256){
      float mu = stats[c]*(1.f/NN);
      float var = stats[KT + c]*(1.f/NN) - mu*mu;
      float g = gamma[c]*rsqrtf(var + BN_EPS);
      scl[c] = g;
      shl[c] = beta[c] - mu*g;
    }
    __syncthreads();
  }

  f32x4 acc[2][4];
  #pragma unroll
  for (int i = 0; i < 2; i++)
    #pragma unroll
    for (int j = 0; j < 4; j++) acc[i][j] = (f32x4){0.f,0.f,0.f,0.f};

  int sr = t >> 3;          // staging row/col 0..31
  int k4 = (t & 7)*4;       // staging k chunk
  int fm = lane & 15;       // fragment row/col
  int fk = (lane >> 4)*8;   // fragment k base

  for (int kb = 0; kb < KT/32; kb++){
    int kbase = kb*32;
    #pragma unroll
    for (int p = 0; p < 2; p++){
      int r = sr + p*32;
      int gn = n0 + r;
      ushort4 v = make_ushort4(0,0,0,0);
      if (gn < NN) v = *reinterpret_cast<const ushort4*>(&Ab[(size_t)gn*KT + kbase + k4]);
      if constexpr (BN){
        int c0 = kbase + k4;
        float f0 = b2f(v.x)*scl[c0+0] + shl[c0+0]; f0 = (f0 > 0.f) ? f0 : (__expf(f0) - 1.f);
        float f1 = b2f(v.y)*scl[c0+1] + shl[c0+1]; f1 = (f1 > 0.f) ? f1 : (__expf(f1) - 1.f);
        float f2 = b2f(v.z)*scl[c0+2] + shl[c0+2]; f2 = (f2 > 0.f) ? f2 : (__expf(f2) - 1.f);
        float f3 = b2f(v.w)*scl[c0+3] + shl[c0+3]; f3 = (f3 > 0.f) ? f3 : (__expf(f3) - 1.f);
        v.x = f2b(f0); v.y = f2b(f1); v.z = f2b(f2); v.w = f2b(f3);
      }
      *reinterpret_cast<ushort4*>(&As[r][k4]) = v;
    }
    #pragma unroll
    for (int q = 0; q < 4; q++){
      int cn = sr + q*32;
      ushort4 v = *reinterpret_cast<const ushort4*>(&Wt[(size_t)(cb0+cn)*KT + kbase + k4]);
      *reinterpret_cast<ushort4*>(&Bs[cn][k4]) = v;
    }
    __syncthreads();
    bf16x8 af0 = *reinterpret_cast<const bf16x8*>(&As[wm*32 + fm][fk]);
    bf16x8 af1 = *reinterpret_cast<const bf16x8*>(&As[wm*32 + 16 + fm][fk]);
    #pragma unroll
    for (int nt = 0; nt < 4; nt++){
      bf16x8 bfr = *reinterpret_cast<const bf16x8*>(&Bs[wn*64 + nt*16 + fm][fk]);
      acc[0][nt] = __builtin_amdgcn_mfma_f32_16x16x32_bf16(af0, bfr, acc[0][nt], 0, 0, 0);
      acc[1][nt] = __builtin_amdgcn_mfma_f32_16x16x32_bf16(af1, bfr, acc[1][nt], 0, 0, 0);
    }
    __syncthreads();
  }

  // epilogue: C/D layout col=lane&15, row=(lane>>4)*4+reg  [m89-verified]
  int frow = (lane >> 4)*4;
  #pragma unroll
  for (int nt = 0; nt < 4; nt++){
    int cn = cb0 + wn*64 + nt*16 + fm;
    bool first = (cn < NOUT);
    int cl = first ? cn : cn - NOUT;
    float bv = first ? ba[cl] : bb[cl];
    u16* Cp = first ? Ca : Cb;
    #pragma unroll
    for (int mt = 0; mt < 2; mt++){
      #pragma unroll
      for (int r = 0; r < 4; r++){
        int grow = n0 + wm*32 + mt*16 + frow + r;
        if (grow < NN) Cp[(size_t)grow*NOUT + cl] = f2b(acc[mt][nt][r] + bv);
      }
    }
  }
}

// ---- Fused GATv2 layer 1: 4x edge unroll (aligned int4 index loads),
//      DPP rotate-reduce, 32-bit gather offsets; bf16 output ----
__global__ __launch_bounds__(256) void k_gat1(const int* __restrict__ ro, const int* __restrict__ ssrc,
      const u16* __restrict__ xl, const u16* __restrict__ xr,
      const float* __restrict__ att, const float* __restrict__ bias,
      u16* __restrict__ out){
  int widx = threadIdx.x >> 6, lane = threadIdx.x & 63;
  int n = blockIdx.x*4 + widx;
  if (n >= NN) return;
  unsigned base = (unsigned)((lane >> 4)*HD + (lane & 15)*4);
  ushort4 ur = *reinterpret_cast<const ushort4*>(&xr[(size_t)n*D1 + base]);
  float xr0 = b2f(ur.x), xr1 = b2f(ur.y), xr2 = b2f(ur.z), xr3 = b2f(ur.w);
  float4 at4 = *reinterpret_cast<const float4*>(&att[base]);
  float a1x = 0.6f*LOG2E*at4.x, a2x = 0.4f*LOG2E*at4.x;
  float a1y = 0.6f*LOG2E*at4.y, a2y = 0.4f*LOG2E*at4.y;
  float a1z = 0.6f*LOG2E*at4.z, a2z = 0.4f*LOG2E*at4.z;
  float a1w = 0.6f*LOG2E*at4.w, a2w = 0.4f*LOG2E*at4.w;
  float m = -1e30f, den = 0.f;
  float ax=0.f, ay=0.f, az=0.f, aw=0.f;
  int b = ro[n], e = ro[n+1];
  int i = b;
  // scalar head to 4-align i for int4 index loads
  int headEnd = min((b + 3) & ~3, e);
  for (; i < headEnd; i++){
    unsigned o0 = (unsigned)ssrc[i]*D1 + base;
    ushort4 u = *reinterpret_cast<const ushort4*>(xl + o0);
    float vx = b2f(u.x), vy = b2f(u.y), vz = b2f(u.z), vw = b2f(u.w);
    float t0 = vx + xr0, t1 = vy + xr1, t2 = vz + xr2, t3 = vw + xr3;
    float L;
    L = fmaf(a1x, t0, a2x*fabsf(t0));
    L = fmaf(a1y, t1, fmaf(a2y, fabsf(t1), L));
    L = fmaf(a1z, t2, fmaf(a2z, fabsf(t2), L));
    L = fmaf(a1w, t3, fmaf(a2w, fabsf(t3), L));
    L = rsum16(L);
    if (__any(L > m + 8.f)){
      float mn = fmaxf(m, L);
      float corr = exp2f(m - mn);
      den *= corr; ax *= corr; ay *= corr; az *= corr; aw *= corr;
      m = mn;
    }
    float p = exp2f(L - m);
    den += p;
    ax = fmaf(p, vx, ax); ay = fmaf(p, vy, ay);
    az = fmaf(p, vz, az); aw = fmaf(p, vw, aw);
  }
  for (; i + 3 < e; i += 4){
    int4 s4 = *reinterpret_cast<const int4*>(&ssrc[i]);
    unsigned o0 = (unsigned)s4.x*D1 + base;
    unsigned o1 = (unsigned)s4.y*D1 + base;
    unsigned o2 = (unsigned)s4.z*D1 + base;
    unsigned o3 = (unsigned)s4.w*D1 + base;
    ushort4 u0 = *reinterpret_cast<const ushort4*>(xl + o0);
    ushort4 u1 = *reinterpret_cast<const ushort4*>(xl + o1);
    ushort4 u2 = *reinterpret_cast<const ushort4*>(xl + o2);
    ushort4 u3 = *reinterpret_cast<const ushort4*>(xl + o3);
    float v0x=b2f(u0.x), v0y=b2f(u0.y), v0z=b2f(u0.z), v0w=b2f(u0.w);
    float v1x=b2f(u1.x), v1y=b2f(u1.y), v1z=b2f(u1.z), v1w=b2f(u1.w);
    float v2x=b2f(u2.x), v2y=b2f(u2.y), v2z=b2f(u2.z), v2w=b2f(u2.w);
    float v3x=b2f(u3.x), v3y=b2f(u3.y), v3z=b2f(u3.z), v3w=b2f(u3.w);
    float t0, t1, t2, t3;
    float L0, L1, L2, L3;
    t0 = v0x+xr0; t1 = v0y+xr1; t2 = v0z+xr2; t3 = v0w+xr3;
    L0 = fmaf(a1x,t0, a2x*fabsf(t0));
    L0 = fmaf(a1y,t1, fmaf(a2y,fabsf(t1), L0));
    L0 = fmaf(a1z,t2, fmaf(a2z,fabsf(t2), L0));
    L0 = fmaf(a1w,t3, fmaf(a2w,fabsf(t3), L0));
    t0 = v1x+xr0; t1 = v1y+xr1; t2 = v1z+xr2; t3 = v1w+xr3;
    L1 = fmaf(a1x,t0, a2x*fabsf(t0));
    L1 = fmaf(a1y,t1, fmaf(a2y,fabsf(t1), L1));
    L1 = fmaf(a1z,t2, fmaf(a2z,fabsf(t2), L1));
    L1 = fmaf(a1w,t3, fmaf(a2w,fabsf(t3), L1));
    t0 = v2x+xr0; t1 = v2y+xr1; t2 = v2z+xr2; t3 = v2w+xr3;
    L2 = fmaf(a1x,t0, a2x*fabsf(t0));
    L2 = fmaf(a1y,t1, fmaf(a2y,fabsf(t1), L2));
    L2 = fmaf(a1z,t2, fmaf(a2z,fabsf(t2), L2));
    L2 = fmaf(a1w,t3, fmaf(a2w,fabsf(t3), L2));
    t0 = v3x+xr0; t1 = v3y+xr1; t2 = v3z+xr2; t3 = v3w+xr3;
    L3 = fmaf(a1x,t0, a2x*fabsf(t0));
    L3 = fmaf(a1y,t1, fmaf(a2y,fabsf(t1), L3));
    L3 = fmaf(a1z,t2, fmaf(a2z,fabsf(t2), L3));
    L3 = fmaf(a1w,t3, fmaf(a2w,fabsf(t3), L3));
    L0 = rsum16(L0); L1 = rsum16(L1);
    L2 = rsum16(L2); L3 = rsum16(L3);
    float Lm = fmaxf(fmaxf(L0, L1), fmaxf(L2, L3));
    if (__any(Lm > m + 8.f)){
      float mn = fmaxf(m, Lm);
      float corr = exp2f(m - mn);
      den *= corr; ax *= corr; ay *= corr; az *= corr; aw *= corr;
      m = mn;
    }
    float p0 = exp2f(L0 - m), p1 = exp2f(L1 - m);
    float p2 = exp2f(L2 - m), p3 = exp2f(L3 - m);
    den += (p0 + p1) + (p2 + p3);
    ax = fmaf(p0,v0x, fmaf(p1,v1x, fmaf(p2,v2x, fmaf(p3,v3x, ax))));
    ay = fmaf(p0,v0y, fmaf(p1,v1y, fmaf(p2,v2y, fmaf(p3,v3y, ay))));
    az = fmaf(p0,v0z, fmaf(p1,v1z, fmaf(p2,v2z, fmaf(p3,v3z, az))));
    aw = fmaf(p0,v0w, fmaf(p1,v1w, fmaf(p2,v2w, fmaf(p3,v3w, aw))));
  }
  for (; i < e; i++){
    unsigned o0 = (unsigned)ssrc[i]*D1 + base;
    ushort4 u = *reinterpret_cast<const ushort4*>(xl + o0);
    float vx = b2f(u.x), vy = b2f(u.y), vz = b2f(u.z), vw = b2f(u.w);
    float t0 = vx + xr0, t1 = vy + xr1, t2 = vz + xr2, t3 = vw + xr3;
    float L;
    L = fmaf(a1x, t0, a2x*fabsf(t0));
    L = fmaf(a1y, t1, fmaf(a2y, fabsf(t1), L));
    L = fmaf(a1z, t2, fmaf(a2z, fabsf(t2), L));
    L = fmaf(a1w, t3, fmaf(a2w, fabsf(t3), L));
    L = rsum16(L);
    if (__any(L > m + 8.f)){
      float mn = fmaxf(m, L);
      float corr = exp2f(m - mn);
      den *= corr; ax *= corr; ay *= corr; az *= corr; aw *= corr;
      m = mn;
    }
    float p = exp2f(L - m);
    den += p;
    ax = fmaf(p, vx, ax); ay = fmaf(p, vy, ay);
    az = fmaf(p, vz, az); aw = fmaf(p, vw, aw);
  }
  float inv = 1.f/den;
  float4 b4 = *reinterpret_cast<const float4*>(&bias[base]);
  ushort4 o;
  o.x = f2b(ax*inv + b4.x); o.y = f2b(ay*inv + b4.y);
  o.z = f2b(az*inv + b4.z); o.w = f2b(aw*inv + b4.w);
  *reinterpret_cast<ushort4*>(&out[(size_t)n*D1 + base]) = o;
}

// ---------------- BatchNorm stats ----------------
__global__ __launch_bounds__(256) void k_bnstats16(const u16* __restrict__ h, float* __restrict__ stats,
                                                   int ncols, int rpb){
  int nrl = 256/ncols;
  int c = threadIdx.x % ncols;
  int rl = threadIdx.x / ncols;
  int r0 = blockIdx.x*rpb + rl;
  int r1 = min(NN, (blockIdx.x+1)*rpb);
  float s = 0.f, s2 = 0.f;
  for (int r = r0; r < r1; r += nrl){
    float v = b2f(h[(size_t)r*ncols + c]);
    s += v; s2 += v*v;
  }
  atomicAdd(&stats[c], s);
  atomicAdd(&stats[ncols + c], s2);
}

__global__ __launch_bounds__(256) void k_bnstats(const float* __restrict__ h, float* __restrict__ stats,
                                                 int ncols, int rpb){
  int nrl = 256/ncols;
  int c = threadIdx.x % ncols;
  int rl = threadIdx.x / ncols;
  int r0 = blockIdx.x*rpb + rl;
  int r1 = min(NN, (blockIdx.x+1)*rpb);
  float s = 0.f, s2 = 0.f;
  for (int r = r0; r < r1; r += nrl){
    float v = h[(size_t)r*ncols + c];
    s += v; s2 += v*v;
  }
  atomicAdd(&stats[c], s);
  atomicAdd(&stats[ncols + c], s2);
}

// ---- Fused GATv2 layer 2 (1 head): 4 lane-groups, 2x unroll, DPP reduce ----
__global__ __launch_bounds__(256) void k_gat2(const int* __restrict__ ro, const int* __restrict__ ssrc,
      const u16* __restrict__ xl, const u16* __restrict__ xr,
      const float* __restrict__ att, const float* __restrict__ bias,
      float* __restrict__ out){
  int widx = threadIdx.x >> 6, lane = threadIdx.x & 63;
  int n = blockIdx.x*4 + widx;
  if (n >= NN) return;
  int g = lane >> 4;
  unsigned c4 = (unsigned)((lane & 15)*4);
  ushort4 ur = *reinterpret_cast<const ushort4*>(&xr[(size_t)n*HD + c4]);
  float xr0 = b2f(ur.x), xr1 = b2f(ur.y), xr2 = b2f(ur.z), xr3 = b2f(ur.w);
  float4 at4 = *reinterpret_cast<const float4*>(&att[c4]);
  float a1x = 0.6f*LOG2E*at4.x, a2x = 0.4f*LOG2E*at4.x;
  float a1y = 0.6f*LOG2E*at4.y, a2y = 0.4f*LOG2E*at4.y;
  float a1z = 0.6f*LOG2E*at4.z, a2z = 0.4f*LOG2E*at4.z;
  float a1w = 0.6f*LOG2E*at4.w, a2w = 0.4f*LOG2E*at4.w;
  float m = -1e30f, den = 0.f;
  float ax=0.f, ay=0.f, az=0.f, aw=0.f;
  int b = ro[n], e = ro[n+1];
  int i = b + g;
  for (; i + 4 < e; i += 8){
    unsigned o0 = (unsigned)ssrc[i  ]*HD + c4;
    unsigned o1 = (unsigned)ssrc[i+4]*HD + c4;
    ushort4 u0 = *reinterpret_cast<const ushort4*>(xl + o0);
    ushort4 u1 = *reinterpret_cast<const ushort4*>(xl + o1);
    float v0x=b2f(u0.x), v0y=b2f(u0.y), v0z=b2f(u0.z), v0w=b2f(u0.w);
    float v1x=b2f(u1.x), v1y=b2f(u1.y), v1z=b2f(u1.z), v1w=b2f(u1.w);
    float t0, t1, t2, t3, L0, L1;
    t0 = v0x+xr0; t1 = v0y+xr1; t2 = v0z+xr2; t3 = v0w+xr3;
    L0 = fmaf(a1x,t0, a2x*fabsf(t0));
    L0 = fmaf(a1y,t1, fmaf(a2y,fabsf(t1), L0));
    L0 = fmaf(a1z,t2, fmaf(a2z,fabsf(t2), L0));
    L0 = fmaf(a1w,t3, fmaf(a2w,fabsf(t3), L0));
    t0 = v1x+xr0; t1 = v1y+xr1; t2 = v1z+xr2; t3 = v1w+xr3;
    L1 = fmaf(a1x,t0, a2x*fabsf(t0));
    L1 = fmaf(a1y,t1, fmaf(a2y,fabsf(t1), L1));
    L1 = fmaf(a1z,t2, fmaf(a2z,fabsf(t2), L1));
    L1 = fmaf(a1w,t3, fmaf(a2w,fabsf(t3), L1));
    L0 = rsum16(L0); L1 = rsum16(L1);
    float Lm = fmaxf(L0, L1);
    if (__any(Lm > m + 8.f)){
      float mn = fmaxf(m, Lm);
      float corr = exp2f(m - mn);
      den *= corr; ax *= corr; ay *= corr; az *= corr; aw *= corr;
      m = mn;
    }
    float p0 = exp2f(L0 - m), p1 = exp2f(L1 - m);
    den += p0 + p1;
    ax = fmaf(p0, v0x, fmaf(p1, v1x, ax));
    ay = fmaf(p0, v0y, fmaf(p1, v1y, ay));
    az = fmaf(p0, v0z, fmaf(p1, v1z, az));
    aw = fmaf(p0, v0w, fmaf(p1, v1w, aw));
  }
  for (; i < e; i += 4){
    unsigned o0 = (unsigned)ssrc[i]*HD + c4;
    ushort4 u = *reinterpret_cast<const ushort4*>(xl + o0);
    float vx = b2f(u.x), vy = b2f(u.y), vz = b2f(u.z), vw = b2f(u.w);
    float t0 = vx + xr0, t1 = vy + xr1, t2 = vz + xr2, t3 = vw + xr3;
    float L;
    L = fmaf(a1x, t0, a2x*fabsf(t0));
    L = fmaf(a1y, t1, fmaf(a2y, fabsf(t1), L));
    L = fmaf(a1z, t2, fmaf(a2z, fabsf(t2), L));
    L = fmaf(a1w, t3, fmaf(a2w, fabsf(t3), L));
    L = rsum16(L);
    if (__any(L > m + 8.f)){
      float mn = fmaxf(m, L);
      float corr = exp2f(m - mn);
      den *= corr; ax *= corr; ay *= corr; az *= corr; aw *= corr;
      m = mn;
    }
    float p = exp2f(L - m);
    den += p;
    ax = fmaf(p, vx, ax);
    ay = fmaf(p, vy, ay);
    az = fmaf(p, vz, az);
    aw = fmaf(p, vw, aw);
  }
  // exact merge of the 4 per-group partials (lanes l^16 / l^32 share c4)
  #pragma unroll
  for (int off = 16; off <= 32; off <<= 1){
    float mo  = __shfl_xor(m, off);
    float dno = __shfl_xor(den, off);
    float bx  = __shfl_xor(ax, off);
    float by  = __shfl_xor(ay, off);
    float bz  = __shfl_xor(az, off);
    float bw  = __shfl_xor(aw, off);
    float mn = fmaxf(m, mo);
    float c1 = exp2f(m - mn), c2 = exp2f(mo - mn);
    den = den*c1 + dno*c2;
    ax = ax*c1 + bx*c2;
    ay = ay*c1 + by*c2;
    az = az*c1 + bz*c2;
    aw = aw*c1 + bw*c2;
    m = mn;
  }
  float inv = 1.f/den;
  float4 b4 = *reinterpret_cast<const float4*>(&bias[c4]);
  float4 o = make_float4(ax*inv + b4.x, ay*inv + b4.y, az*inv + b4.z, aw*inv + b4.w);
  *reinterpret_cast<float4*>(&out[(size_t)n*HD + c4]) = o;
}

// BN2 + ELU + pooled sums, sorted-batch strip reduction (25 nodes/wave)
__global__ __launch_bounds__(256) void k_bn2pool(const float* __restrict__ h2, const float* __restrict__ stats,
      const float* __restrict__ gamma, const float* __restrict__ beta,
      const int* __restrict__ batch, float* __restrict__ pool, float* __restrict__ pcnt){
  int wave = blockIdx.x*4 + (threadIdx.x >> 6);
  int lane = threadIdx.x & 63;
  int n0 = wave*PW_NODES;
  if (n0 >= NN) return;
  int n1 = min(NN, n0 + PW_NODES);
  const float invn = 1.f/NN;
  float mu = stats[lane]*invn;
  float var = stats[HD + lane]*invn - mu*mu;
  float sc = gamma[lane]*rsqrtf(var + BN_EPS);
  float sh = beta[lane] - mu*sc;
  int curg = batch[n0];
  float acc = 0.f, cnt = 0.f;
  for (int n = n0; n < n1; n++){
    int g = batch[n];
    if (g != curg){
      atomicAdd(&pool[curg*HD + lane], acc);
      if (lane == 0) atomicAdd(&pcnt[curg], cnt);
      acc = 0.f; cnt = 0.f; curg = g;
    }
    float v = h2[(size_t)n*HD + lane]*sc + sh;
    v = (v > 0.f) ? v : (__expf(v) - 1.f);
    acc += v; cnt += 1.f;
  }
  atomicAdd(&pool[curg*HD + lane], acc);
  if (lane == 0) atomicAdd(&pcnt[curg], cnt);
}

// final MLP: out[g] = elu(pooled@lw1+lb1) @ lw2 + lb2   (f32 output)
__global__ __launch_bounds__(64) void k_mlp(const float* __restrict__ pool, const float* __restrict__ pcnt,
      const float* __restrict__ lw1, const float* __restrict__ lb1,
      const float* __restrict__ lw2, const float* __restrict__ lb2, float* __restrict__ out){
  __shared__ float p[HD];
  int g = blockIdx.x, c = threadIdx.x;
  float cnt = fmaxf(pcnt[g], 1.f);
  p[c] = pool[g*HD + c]/cnt;
  __syncthreads();
  float acc = lb1[c];
  for (int k = 0; k < HD; k++) acc += p[k]*lw1[k*HD + c];
  acc = (acc > 0.f) ? acc : (__expf(acc) - 1.f);
  float t = acc * lw2[c];
  #pragma unroll
  for (int off = 32; off > 0; off >>= 1) t += __shfl_xor(t, off, 64);
  if (c == 0) out[g] = t + lb2[0];
}

extern "C" void kernel_launch(void* const* d_in, const int* in_sizes, int n_in,
                              void* d_out, int out_size, void* d_ws, size_t ws_size,
                              hipStream_t stream){
  const float* x    = (const float*)d_in[0];
  const int*  ei    = (const int*) d_in[1];
  const int*  batch = (const int*) d_in[2];
  const float* W1l = (const float*)d_in[3];
  const float* b1l = (const float*)d_in[4];
  const float* W1r = (const float*)d_in[5];
  const float* b1r = (const float*)d_in[6];
  const float* att1= (const float*)d_in[7];
  const float* bias1=(const float*)d_in[8];
  const float* gamma1=(const float*)d_in[9];
  const float* beta1 =(const float*)d_in[10];
  const float* W2l = (const float*)d_in[11];
  const float* b2l = (const float*)d_in[12];
  const float* W2r = (const float*)d_in[13];
  const float* b2r = (const float*)d_in[14];
  const float* att2= (const float*)d_in[15];
  const float* bias2=(const float*)d_in[16];
  const float* gamma2=(const float*)d_in[17];
  const float* beta2 =(const float*)d_in[18];
  const float* lw1 = (const float*)d_in[19];
  const float* lb1 = (const float*)d_in[20];
  const float* lw2 = (const float*)d_in[21];
  const float* lb2 = (const float*)d_in[22];
  float* out = (float*)d_out;

  char* w = (char*)d_ws;
  size_t off = 0;
  auto take = [&](size_t bytes)->char*{
    char* p = w + off;
    off = (off + bytes + 255) & ~(size_t)255;
    return p;
  };
  int*   ro    = (int*)  take((NN+1)*sizeof(int));
  int*   cur   = (int*)  take((size_t)NN*sizeof(int));
  int*   ssrc  = (int*)  take((size_t)ET*sizeof(int));
  int*   part  = (int*)  take(64*sizeof(int));
  float* stats1= (float*)take(2*D1*sizeof(float));
  float* stats2= (float*)take(2*HD*sizeof(float));
  float* pool  = (float*)take(NG*HD*sizeof(float));
  float* pcnt  = (float*)take(NG*sizeof(float));
  u16*   xb    = (u16*)  take((size_t)NN*IND*sizeof(u16));
  u16*   Wt1   = (u16*)  take((size_t)2*D1*IND*sizeof(u16));   // [512][128]
  u16*   Wt2   = (u16*)  take((size_t)2*HD*D1*sizeof(u16));    // [128][256]
  char*  bufA  = take((size_t)NN*D1*2*sizeof(u16));            // xlb1+xrb1; later xlb2+xrb2+h2
  u16*   h1    = (u16*)  take((size_t)NN*D1*sizeof(u16));      // bf16 h1 (raw, pre-BN)

  u16* xlb1 = (u16*)bufA;
  u16* xrb1 = xlb1 + (size_t)NN*D1;
  u16* xlb2 = (u16*)bufA;                                      // overlays dead xlb1
  u16* xrb2 = xlb2 + (size_t)NN*HD;
  float* h2 = (float*)(bufA + (size_t)2*NN*HD*sizeof(u16));

  // mega-prep: casts + weight transposes + zero cur/stats/pool/pcnt
  k_prep<<<(PTOT + 255)/256, 256, 0, stream>>>(x, xb, W1l, W1r, Wt1, W2l, W2r, Wt2,
                                               cur, stats1, stats2, pool, pcnt);

  // CSR build: count -> 3-kernel scan (scan3 re-zeroes cur) -> scatter
  k_count<<<(ET+255)/256, 256, 0, stream>>>(ei, cur);
  int nsb = (NN + 1023)/1024;                       // 49 blocks
  k_scan1<<<nsb, 1024, 0, stream>>>(cur, ro, part);
  k_scan2<<<1, 64, 0, stream>>>(part, nsb);
  k_scan3<<<nsb, 1024, 0, stream>>>(part, ro, cur);
  k_scatter<<<(ET+255)/256, 256, 0, stream>>>(ei, ro, cur, ssrc);

  const int MB = (NN + 63)/64;                      // 782 row tiles

  // Layer 1: MFMA dual GEMM (bf16) then fused gather+softmax+aggregate
  k_gemm<IND, D1, false><<<dim3(MB, 4), 256, 0, stream>>>(xb, Wt1, b1l, b1r,
        nullptr, nullptr, nullptr, xlb1, xrb1);
  k_gat1<<<(NN+3)/4, 256, 0, stream>>>(ro, ssrc, xlb1, xrb1, att1, bias1, h1);
  k_bnstats16<<<196, 256, 0, stream>>>(h1, stats1, D1, 256);

  // Layer 2: BN1+ELU fused into A-staging of gemm2
  k_gemm<D1, HD, true><<<dim3(MB, 1), 256, 0, stream>>>(h1, Wt2, b2l, b2r,
        stats1, gamma1, beta1, xlb2, xrb2);
  k_gat2<<<(NN+3)/4, 256, 0, stream>>>(ro, ssrc, xlb2, xrb2, att2, bias2, h2);
  k_bnstats<<<196, 256, 0, stream>>>(h2, stats2, HD, 256);

  // BN2 + ELU + pool (sorted-batch strip reduction), then MLP head
  {
    int waves = (NN + PW_NODES - 1)/PW_NODES;       // 2000
    int blocks = (waves + 3)/4;                      // 500
    k_bn2pool<<<blocks, 256, 0, stream>>>(h2, stats2, gamma2, beta2, batch, pool, pcnt);
  }
  k_mlp<<<NG, 64, 0, stream>>>(pool, pcnt, lw1, lb1, lw2, lb2, out);
}